// Round 14
// baseline (349.282 us; speedup 1.0000x reference)
//
#include <hip/hip_runtime.h>
#include <hip/hip_bf16.h>
#include <stdint.h>

// ---- All intermediates live inside d_out (16,777,216 f32; 256 slots x 65536 f32).
// Slot q (q=b*64+co): [0,4096) feat plane q ; [4096,8192) cat plane p (p<256, p&255==q)
// [8192,12288) cat plane p (p>=256) ; [12288] mean ; [12289] att ;
// [16384,24576) f64 x1_hi plane q ; [25600,26112) wT chunks (slots 0..143);
// [26112,26624) wdT chunks (slots 0..127).
__device__ __forceinline__ float* catp(float* o, int p) {
    return o + (size_t)(p & 255) * 65536 + 4096 + ((p >> 8) << 12);
}
__device__ __forceinline__ double* x1hp(float* o, int q) {
    return (double*)(o + (size_t)q * 65536 + 16384);
}
__device__ __forceinline__ float wtv(const float* o, int kk, int co) {
    return o[(size_t)(kk >> 3) * 65536 + 25600 + (kk & 7) * 64 + co];
}

// ---------------- K0: transpose w1 -> wT[kk][co]; wd -> wdT[kk2][co]
__global__ __launch_bounds__(256) void k0_wtrans(const float* __restrict__ w1, const float* __restrict__ wd,
                                                 float* __restrict__ o) {
    int idx = blockIdx.x * 256 + threadIdx.x;
    if (idx < 73728) {
        int co = idx & 63, kk = idx >> 6;
        o[(size_t)(kk >> 3) * 65536 + 25600 + (kk & 7) * 64 + co] = w1[co * 1152 + kk];
    } else if (idx < 73728 + 65536) {
        int j = idx - 73728;
        int co = j & 63, kk2 = j >> 6;   // kk2 = ci*16 + ky*4 + kx, < 1024
        o[(size_t)(kk2 >> 3) * 65536 + 26112 + (kk2 & 7) * 64 + co] = wd[co * 1024 + kk2];
    }
}

// ---------------- K1: 4x4/stride-4 conv + BN + ReLU in f64 -> f32 cat ch 0..63 + f64 x1_hi
// grid: 512 = B(4)*I(64)*Jt(2); block 256. LDS 32KB. 8 outputs/thread. Coalesced wdT loads.
__global__ __launch_bounds__(256) void k1_convds(
    const float* __restrict__ x, const float* __restrict__ bd,
    const float* __restrict__ g, const float* __restrict__ be,
    const float* __restrict__ m, const float* __restrict__ v,
    float* __restrict__ o)
{
    __shared__ __align__(16) float tile[16 * 4 * 128];
    int blk = blockIdx.x;
    int jt = blk & 1, i = (blk >> 1) & 63, b = blk >> 7;
    int t = threadIdx.x;
    int co = t & 63, jg = t >> 6;
    double acc0 = 0.0, acc1 = 0.0, acc2 = 0.0, acc3 = 0.0;
    double acc4 = 0.0, acc5 = 0.0, acc6 = 0.0, acc7 = 0.0;
    for (int st = 0; st < 4; ++st) {
        __syncthreads();
        for (int kk = 0; kk < 8; ++kk) {
            int ch = t + 256 * kk;
            int ci = ch >> 7, y4 = (ch >> 5) & 3, x4 = ch & 31;
            const float* src = x + (((b * 64 + st * 16 + ci) * 256 + (i * 4 + y4)) * 256 + jt * 128 + x4 * 4);
            *(float4*)(tile + (ci * 4 + y4) * 128 + x4 * 4) = *(const float4*)src;
        }
        __syncthreads();
        for (int ci = 0; ci < 16; ++ci) {
            #pragma unroll
            for (int ky = 0; ky < 4; ++ky) {
                int kk2 = (st * 16 + ci) * 16 + ky * 4;
                const float* wp = o + (size_t)(kk2 >> 3) * 65536 + 26112 + (kk2 & 7) * 64 + co;
                double w0 = (double)wp[0], w1d = (double)wp[64], w2d = (double)wp[128], w3d = (double)wp[192];
                const float* xr = tile + (ci * 4 + ky) * 128 + jg * 32;
                float4 a0 = *(const float4*)(xr);
                float4 a1 = *(const float4*)(xr + 4);
                float4 a2 = *(const float4*)(xr + 8);
                float4 a3 = *(const float4*)(xr + 12);
                float4 a4 = *(const float4*)(xr + 16);
                float4 a5 = *(const float4*)(xr + 20);
                float4 a6 = *(const float4*)(xr + 24);
                float4 a7 = *(const float4*)(xr + 28);
                acc0 = fma(w0, (double)a0.x, fma(w1d, (double)a0.y, fma(w2d, (double)a0.z, fma(w3d, (double)a0.w, acc0))));
                acc1 = fma(w0, (double)a1.x, fma(w1d, (double)a1.y, fma(w2d, (double)a1.z, fma(w3d, (double)a1.w, acc1))));
                acc2 = fma(w0, (double)a2.x, fma(w1d, (double)a2.y, fma(w2d, (double)a2.z, fma(w3d, (double)a2.w, acc2))));
                acc3 = fma(w0, (double)a3.x, fma(w1d, (double)a3.y, fma(w2d, (double)a3.z, fma(w3d, (double)a3.w, acc3))));
                acc4 = fma(w0, (double)a4.x, fma(w1d, (double)a4.y, fma(w2d, (double)a4.z, fma(w3d, (double)a4.w, acc4))));
                acc5 = fma(w0, (double)a5.x, fma(w1d, (double)a5.y, fma(w2d, (double)a5.z, fma(w3d, (double)a5.w, acc5))));
                acc6 = fma(w0, (double)a6.x, fma(w1d, (double)a6.y, fma(w2d, (double)a6.z, fma(w3d, (double)a6.w, acc6))));
                acc7 = fma(w0, (double)a7.x, fma(w1d, (double)a7.y, fma(w2d, (double)a7.z, fma(w3d, (double)a7.w, acc7))));
            }
        }
    }
    double sc = (double)g[co] / sqrt((double)v[co] + 1e-5);
    double sh = (double)bd[co] - (double)m[co];
    double bb = (double)be[co];
    double o0 = fmax(0.0, (acc0 + sh) * sc + bb);
    double o1 = fmax(0.0, (acc1 + sh) * sc + bb);
    double o2 = fmax(0.0, (acc2 + sh) * sc + bb);
    double o3 = fmax(0.0, (acc3 + sh) * sc + bb);
    double o4 = fmax(0.0, (acc4 + sh) * sc + bb);
    double o5 = fmax(0.0, (acc5 + sh) * sc + bb);
    double o6 = fmax(0.0, (acc6 + sh) * sc + bb);
    double o7 = fmax(0.0, (acc7 + sh) * sc + bb);
    int pos = i * 64 + jt * 32 + jg * 8;
    float4 ovA, ovB;
    ovA.x = (float)o0; ovA.y = (float)o1; ovA.z = (float)o2; ovA.w = (float)o3;
    ovB.x = (float)o4; ovB.y = (float)o5; ovB.z = (float)o6; ovB.w = (float)o7;
    float* cp = catp(o, b * 128 + co);
    *(float4*)(cp + pos) = ovA;
    *(float4*)(cp + pos + 4) = ovB;
    double* xh = x1hp(o, b * 64 + co);
    *(double2*)(xh + pos)     = make_double2(o0, o1);
    *(double2*)(xh + pos + 2) = make_double2(o2, o3);
    *(double2*)(xh + pos + 4) = make_double2(o4, o5);
    *(double2*)(xh + pos + 6) = make_double2(o6, o7);
}

// ---------------- K2: windowed d^2 (f64) -> top-9 -> f32 neighbor-mean diff. block 512.
__global__ __launch_bounds__(512) void k2_feat(float* __restrict__ o)
{
    __shared__ __align__(16) char smem[15232];
    __shared__ double dotsd[64 * 50];
    __shared__ double sqd[7 * 64];
    __shared__ int sels[64 * 9];
    double* tile_d = (double*)smem;
    float* tileq = (float*)smem;
    int blk = blockIdx.x;
    int b = blk >> 6, i = blk & 63;
    int t = threadIdx.x;
    int lane = t & 63, wv = t >> 6;

    for (int p = t; p < 64 * 50; p += 512) dotsd[p] = 0.0;
    for (int p = t; p < 448; p += 512) sqd[p] = 0.0;

    for (int q = 0; q < 16; ++q) {
        __syncthreads();
        for (int s = t; s < 896; s += 512) {
            int rc = s >> 5, c2 = s & 31;
            int r = rc >> 2, c = rc & 3;
            int gr = i - 3 + r;
            if (gr >= 0 && gr <= 63) {
                const double* src = x1hp(o, b * 64 + q * 4 + c);
                *(double2*)(tile_d + rc * 66 + c2 * 2) = *(const double2*)(src + gr * 64 + c2 * 2);
            }
        }
        __syncthreads();
        for (int p = t; p < 448; p += 512) {
            int r = p >> 6, col = p & 63;
            int gr = i - 3 + r;
            if (gr >= 0 && gr <= 63) {
                double s = 0.0;
                #pragma unroll
                for (int c = 0; c < 4; ++c) {
                    double xv = tile_d[(r * 4 + c) * 66 + col];
                    s = fma(xv, xv, s);
                }
                sqd[p] += s;
            }
        }
        double xlq[4];
        #pragma unroll
        for (int c = 0; c < 4; ++c) xlq[c] = tile_d[(12 + c) * 66 + lane];
        for (int oo = wv; oo < 49; oo += 8) {
            int oi = oo / 7 - 3, oj = oo % 7 - 3;
            int mi = i + oi, mj = lane + oj;
            if (mi >= 0 && mi <= 63 && mj >= 0 && mj <= 63) {
                int r = oi + 3;
                double dot = 0.0;
                #pragma unroll
                for (int c = 0; c < 4; ++c) dot = fma(xlq[c], tile_d[(r * 4 + c) * 66 + mj], dot);
                dotsd[lane * 50 + oo] += dot;
            }
        }
    }
    __syncthreads();
    for (int oo = wv; oo < 49; oo += 8) {
        int oi = oo / 7 - 3, oj = oo % 7 - 3;
        int mi = i + oi, mj = lane + oj;
        double d2 = -1e300;
        if (mi >= 0 && mi <= 63 && mj >= 0 && mj <= 63)
            d2 = sqd[192 + lane] + sqd[(oi + 3) * 64 + mj] - 2.0 * dotsd[lane * 50 + oo];
        dotsd[lane * 50 + oo] = d2;
    }
    __syncthreads();
    if (wv == 0) {
        unsigned long long mask = 0ull;
        for (int k = 0; k < 9; ++k) {
            double best = -1e308; int bi = 0;
            for (int oo = 0; oo < 49; ++oo) {
                if ((mask >> oo) & 1ull) continue;
                double vv = dotsd[lane * 50 + oo];
                if (vv > best) { best = vv; bi = oo; }
            }
            mask |= (1ull << bi);
            sels[lane * 9 + k] = bi;
        }
    }
    __syncthreads();
    int rk[9], cj[9];
    #pragma unroll
    for (int k = 0; k < 9; ++k) {
        int oo = sels[lane * 9 + k];
        rk[k] = oo / 7;
        cj[k] = lane + (oo % 7) - 3;
    }
    for (int q = 0; q < 8; ++q) {
        __syncthreads();
        for (int s = t; s < 896; s += 512) {
            int rc = s >> 4, x4 = s & 15;
            int r = rc >> 3, c = rc & 7;
            int gr = i - 3 + r;
            if (gr >= 0 && gr <= 63)
                *(float4*)(tileq + rc * 68 + x4 * 4) =
                    *(const float4*)(catp(o, b * 128 + q * 8 + c) + gr * 64 + x4 * 4);
        }
        __syncthreads();
        {
            int c = wv;
            float s = 0.f;
            #pragma unroll
            for (int k = 0; k < 9; ++k) s += tileq[(rk[k] * 8 + c) * 68 + cj[k]];
            float outv = s * (1.f / 9.f) - tileq[(24 + c) * 68 + lane];
            catp(o, b * 128 + 64 + q * 8 + c)[i * 64 + lane] = outv;
        }
    }
}

// ---------------- K3: 3x3 conv (128->64) + BN + ReLU, LDS-staged weights+inputs
// grid: 256 = B*64 rows; block 1024. LDS 49.5KB. 8 stages of 16 ci.
__global__ __launch_bounds__(1024) void k3_conv(
    float* __restrict__ o, const float* __restrict__ b1,
    const float* __restrict__ g, const float* __restrict__ be,
    const float* __restrict__ m, const float* __restrict__ v)
{
    __shared__ __align__(16) float wlds[16 * 9 * 64];
    __shared__ __align__(16) float xlds[3 * 16 * 72];
    int blk = blockIdx.x;
    int b = blk >> 6, i = blk & 63;
    int t = threadIdx.x;
    int co = t & 63, jg = t >> 6;
    float acc0 = 0.f, acc1 = 0.f, acc2 = 0.f, acc3 = 0.f;
    const float4 z4 = make_float4(0.f, 0.f, 0.f, 0.f);
    for (int st = 0; st < 8; ++st) {
        __syncthreads();
        for (int idx = t; idx < 9216; idx += 1024) {
            int kk = st * 144 + (idx >> 6);
            wlds[idx] = wtv(o, kk, idx & 63);
        }
        for (int f = t; f < 864; f += 1024) {
            int x4 = f % 18, rc = f / 18;
            int ry = rc >> 4, cl = rc & 15;
            int gr = i - 1 + ry;
            float4 val = z4;
            if (x4 >= 1 && x4 <= 16 && gr >= 0 && gr <= 63)
                val = *(const float4*)(catp(o, b * 128 + st * 16 + cl) + gr * 64 + (x4 - 1) * 4);
            *(float4*)(xlds + rc * 72 + x4 * 4) = val;
        }
        __syncthreads();
        for (int cl = 0; cl < 16; ++cl) {
            #pragma unroll
            for (int ry = 0; ry < 3; ++ry) {
                float w0  = wlds[(cl * 9 + ry * 3 + 0) * 64 + co];
                float w1f = wlds[(cl * 9 + ry * 3 + 1) * 64 + co];
                float w2  = wlds[(cl * 9 + ry * 3 + 2) * 64 + co];
                const float* xr = xlds + (ry * 16 + cl) * 72 + jg * 4;
                float4 q0 = *(const float4*)(xr);
                float4 q1 = *(const float4*)(xr + 4);
                float4 q2 = *(const float4*)(xr + 8);
                float xv[12] = { q0.x,q0.y,q0.z,q0.w, q1.x,q1.y,q1.z,q1.w, q2.x,q2.y,q2.z,q2.w };
                acc0 = fmaf(w0, xv[3], fmaf(w1f, xv[4], fmaf(w2, xv[5], acc0)));
                acc1 = fmaf(w0, xv[4], fmaf(w1f, xv[5], fmaf(w2, xv[6], acc1)));
                acc2 = fmaf(w0, xv[5], fmaf(w1f, xv[6], fmaf(w2, xv[7], acc2)));
                acc3 = fmaf(w0, xv[6], fmaf(w1f, xv[7], fmaf(w2, xv[8], acc3)));
            }
        }
    }
    float sc = g[co] * rsqrtf(v[co] + 1e-5f);
    float sh = b1[co] - m[co];
    float bb = be[co];
    float4 ov;
    ov.x = fmaxf(0.f, fmaf(acc0 + sh, sc, bb));
    ov.y = fmaxf(0.f, fmaf(acc1 + sh, sc, bb));
    ov.z = fmaxf(0.f, fmaf(acc2 + sh, sc, bb));
    ov.w = fmaxf(0.f, fmaf(acc3 + sh, sc, bb));
    *(float4*)(o + (size_t)(b * 64 + co) * 65536 + i * 64 + jg * 4) = ov;
}

// ---------------- K4a: per-plane spatial mean -> slot[12288]
__global__ __launch_bounds__(256) void k4_mean(float* __restrict__ o) {
    int q = blockIdx.x, t = threadIdx.x;
    const float* p = o + (size_t)q * 65536;
    float s = 0.f;
    for (int k = t; k < 4096; k += 256) s += p[k];
    #pragma unroll
    for (int off = 32; off > 0; off >>= 1) s += __shfl_down(s, off, 64);
    __shared__ float red[4];
    if ((t & 63) == 0) red[t >> 6] = s;
    __syncthreads();
    if (t == 0) o[(size_t)q * 65536 + 12288] = (red[0] + red[1] + red[2] + red[3]) * (1.f / 4096.f);
}

// ---------------- K4b: 1x1 conv + BN + sigmoid -> slot[12289]
__global__ __launch_bounds__(256) void k4_att(float* __restrict__ o, const float* __restrict__ wa,
    const float* __restrict__ g, const float* __restrict__ be, const float* __restrict__ m, const float* __restrict__ v) {
    int t = threadIdx.x;
    int b = t >> 6, co = t & 63;
    const float* wr = wa + co * 64;
    float s = 0.f;
    for (int ci = 0; ci < 64; ++ci) s = fmaf(wr[ci], o[(size_t)(b * 64 + ci) * 65536 + 12288], s);
    float sc = g[co] * rsqrtf(v[co] + 1e-5f);
    float y = fmaf(s - m[co], sc, be[co]);
    o[(size_t)t * 65536 + 12289] = 1.f / (1.f + expf(-y));
}

// ---------------- K5: out = bilinear_x4(feat)*att, in place over own slot. block 1024.
__global__ __launch_bounds__(1024) void k5_up(float* __restrict__ o) {
    __shared__ __align__(16) float fplane[4096];
    int bc = blockIdx.x;
    int t = threadIdx.x;
    float* slot = o + (size_t)bc * 65536;
    *(float4*)(fplane + t * 4) = *(const float4*)(slot + t * 4);
    float att = slot[12289];
    __syncthreads();
    int ox = t & 255, oyc = t >> 8;
    float fx = ox * 0.25f - 0.375f;
    int ix = (int)floorf(fx);
    float wx = fx - (float)ix;
    int x0 = ix < 0 ? 0 : ix;
    int x1 = (ix + 1 > 63) ? 63 : ix + 1;
    for (int oy = oyc * 64; oy < oyc * 64 + 64; ++oy) {
        float fy = oy * 0.25f - 0.375f;
        int iy = (int)floorf(fy);
        float wy = fy - (float)iy;
        int y0 = iy < 0 ? 0 : iy;
        int y1 = (iy + 1 > 63) ? 63 : iy + 1;
        float a  = fplane[y0 * 64 + x0], b_ = fplane[y0 * 64 + x1];
        float c_ = fplane[y1 * 64 + x0], d_ = fplane[y1 * 64 + x1];
        float top = a + wx * (b_ - a);
        float bot = c_ + wx * (d_ - c_);
        float val = (top + wy * (bot - top)) * att;
        slot[oy * 256 + ox] = val;
    }
}

extern "C" void kernel_launch(void* const* d_in, const int* in_sizes, int n_in,
                              void* d_out, int out_size, void* d_ws, size_t ws_size,
                              hipStream_t stream) {
    const float* x     = (const float*)d_in[0];
    const float* wd    = (const float*)d_in[1];
    const float* bd    = (const float*)d_in[2];
    const float* bnd_g = (const float*)d_in[3];
    const float* bnd_b = (const float*)d_in[4];
    const float* bnd_m = (const float*)d_in[5];
    const float* bnd_v = (const float*)d_in[6];
    const float* w1    = (const float*)d_in[7];
    const float* b1    = (const float*)d_in[8];
    const float* bn1_g = (const float*)d_in[9];
    const float* bn1_b = (const float*)d_in[10];
    const float* bn1_m = (const float*)d_in[11];
    const float* bn1_v = (const float*)d_in[12];
    const float* wa    = (const float*)d_in[13];
    const float* bna_g = (const float*)d_in[14];
    const float* bna_b = (const float*)d_in[15];
    const float* bna_m = (const float*)d_in[16];
    const float* bna_v = (const float*)d_in[17];

    float* o = (float*)d_out;

    hipLaunchKernelGGL(k0_wtrans, dim3(544), dim3(256), 0, stream, w1, wd, o);
    hipLaunchKernelGGL(k1_convds, dim3(512), dim3(256), 0, stream,
                       x, bd, bnd_g, bnd_b, bnd_m, bnd_v, o);
    hipLaunchKernelGGL(k2_feat, dim3(256), dim3(512), 0, stream, o);
    hipLaunchKernelGGL(k3_conv, dim3(256), dim3(1024), 0, stream,
                       o, b1, bn1_g, bn1_b, bn1_m, bn1_v);
    hipLaunchKernelGGL(k4_mean, dim3(256), dim3(256), 0, stream, o);
    hipLaunchKernelGGL(k4_att, dim3(1), dim3(256), 0, stream,
                       o, wa, bna_g, bna_b, bna_m, bna_v);
    hipLaunchKernelGGL(k5_up, dim3(256), dim3(1024), 0, stream, o);
}

// Round 15
// 294.329 us; speedup vs baseline: 1.1867x; 1.1867x over previous
//
#include <hip/hip_runtime.h>
#include <hip/hip_bf16.h>
#include <stdint.h>

// ---- All intermediates live inside d_out (16,777,216 f32; 256 slots x 65536 f32).
// Slot q (q=b*64+co): [0,4096) feat plane q ; [4096,8192) cat plane p (p<256, p&255==q)
// [8192,12288) cat plane p (p>=256) ; [12288] mean ; [12289] att ;
// [16384,24576) f64 x1_hi plane q ; [25600,26112) wT chunks (slots 0..143).
__device__ __forceinline__ float* catp(float* o, int p) {
    return o + (size_t)(p & 255) * 65536 + 4096 + ((p >> 8) << 12);
}
__device__ __forceinline__ double* x1hp(float* o, int q) {
    return (double*)(o + (size_t)q * 65536 + 16384);
}
__device__ __forceinline__ float wtv(const float* o, int kk, int co) {
    return o[(size_t)(kk >> 3) * 65536 + 25600 + (kk & 7) * 64 + co];
}

// ---------------- K0: transpose w1 (64,128,3,3) -> wT[kk][co]
__global__ __launch_bounds__(256) void k0_wtrans(const float* __restrict__ w1, float* __restrict__ o) {
    int idx = blockIdx.x * 256 + threadIdx.x;
    if (idx >= 73728) return;
    int co = idx & 63, kk = idx >> 6;
    o[(size_t)(kk >> 3) * 65536 + 25600 + (kk & 7) * 64 + co] = w1[co * 1152 + kk];
}

// ---------------- K1: 4x4/stride-4 conv + BN + ReLU in f64 -> f32 cat ch 0..63 + f64 x1_hi
// grid: 512 = B(4)*I(64)*Jt(2); block 256. LDS 32KB f64 tile (8 stages of 8 ci).
// Inputs converted to f64 ONCE at staging; hot loop has no input cvts.
__global__ __launch_bounds__(256) void k1_convds(
    const float* __restrict__ x, const float* __restrict__ wd, const float* __restrict__ bd,
    const float* __restrict__ g, const float* __restrict__ be,
    const float* __restrict__ m, const float* __restrict__ v,
    float* __restrict__ o)
{
    __shared__ __align__(16) double tile[8 * 4 * 128];   // 32KB
    int blk = blockIdx.x;
    int jt = blk & 1, i = (blk >> 1) & 63, b = blk >> 7;
    int t = threadIdx.x;
    int co = t & 63, jg = t >> 6;   // 8 outputs j = jt*32 + jg*8 + {0..7}
    double acc0 = 0.0, acc1 = 0.0, acc2 = 0.0, acc3 = 0.0;
    double acc4 = 0.0, acc5 = 0.0, acc6 = 0.0, acc7 = 0.0;
    for (int st = 0; st < 8; ++st) {
        __syncthreads();
        // stage 8ci x 4ky x 128 cols: 1024 float4 chunks -> f64 LDS
        for (int kk = 0; kk < 4; ++kk) {
            int ch = t + 256 * kk;
            int ci = ch >> 7, y4 = (ch >> 5) & 3, x4 = ch & 31;
            const float* src = x + (((b * 64 + st * 8 + ci) * 256 + (i * 4 + y4)) * 256 + jt * 128 + x4 * 4);
            float4 f = *(const float4*)src;
            double* dst = tile + (ci * 4 + y4) * 128 + x4 * 4;
            dst[0] = (double)f.x; dst[1] = (double)f.y; dst[2] = (double)f.z; dst[3] = (double)f.w;
        }
        __syncthreads();
        const float* wco = wd + co * 1024 + st * 128;
        for (int ci = 0; ci < 8; ++ci) {
            #pragma unroll
            for (int ky = 0; ky < 4; ++ky) {
                float4 wv4 = *(const float4*)(wco + ci * 16 + ky * 4);
                double w0 = (double)wv4.x, w1d = (double)wv4.y, w2d = (double)wv4.z, w3d = (double)wv4.w;
                const double* xr = tile + (ci * 4 + ky) * 128 + jg * 32;
                acc0 = fma(w0, xr[0],  fma(w1d, xr[1],  fma(w2d, xr[2],  fma(w3d, xr[3],  acc0))));
                acc1 = fma(w0, xr[4],  fma(w1d, xr[5],  fma(w2d, xr[6],  fma(w3d, xr[7],  acc1))));
                acc2 = fma(w0, xr[8],  fma(w1d, xr[9],  fma(w2d, xr[10], fma(w3d, xr[11], acc2))));
                acc3 = fma(w0, xr[12], fma(w1d, xr[13], fma(w2d, xr[14], fma(w3d, xr[15], acc3))));
                acc4 = fma(w0, xr[16], fma(w1d, xr[17], fma(w2d, xr[18], fma(w3d, xr[19], acc4))));
                acc5 = fma(w0, xr[20], fma(w1d, xr[21], fma(w2d, xr[22], fma(w3d, xr[23], acc5))));
                acc6 = fma(w0, xr[24], fma(w1d, xr[25], fma(w2d, xr[26], fma(w3d, xr[27], acc6))));
                acc7 = fma(w0, xr[28], fma(w1d, xr[29], fma(w2d, xr[30], fma(w3d, xr[31], acc7))));
            }
        }
    }
    double sc = (double)g[co] / sqrt((double)v[co] + 1e-5);
    double sh = (double)bd[co] - (double)m[co];
    double bb = (double)be[co];
    double o0 = fmax(0.0, (acc0 + sh) * sc + bb);
    double o1 = fmax(0.0, (acc1 + sh) * sc + bb);
    double o2 = fmax(0.0, (acc2 + sh) * sc + bb);
    double o3 = fmax(0.0, (acc3 + sh) * sc + bb);
    double o4 = fmax(0.0, (acc4 + sh) * sc + bb);
    double o5 = fmax(0.0, (acc5 + sh) * sc + bb);
    double o6 = fmax(0.0, (acc6 + sh) * sc + bb);
    double o7 = fmax(0.0, (acc7 + sh) * sc + bb);
    int pos = i * 64 + jt * 32 + jg * 8;
    float4 ovA, ovB;
    ovA.x = (float)o0; ovA.y = (float)o1; ovA.z = (float)o2; ovA.w = (float)o3;
    ovB.x = (float)o4; ovB.y = (float)o5; ovB.z = (float)o6; ovB.w = (float)o7;
    float* cp = catp(o, b * 128 + co);
    *(float4*)(cp + pos) = ovA;
    *(float4*)(cp + pos + 4) = ovB;
    double* xh = x1hp(o, b * 64 + co);
    *(double2*)(xh + pos)     = make_double2(o0, o1);
    *(double2*)(xh + pos + 2) = make_double2(o2, o3);
    *(double2*)(xh + pos + 4) = make_double2(o4, o5);
    *(double2*)(xh + pos + 6) = make_double2(o6, o7);
}

// ---------------- K2: windowed d^2 (f64) -> top-9 -> f32 neighbor-mean diff. block 512.
__global__ __launch_bounds__(512) void k2_feat(float* __restrict__ o)
{
    __shared__ __align__(16) char smem[15232];
    __shared__ double dotsd[64 * 50];
    __shared__ double sqd[7 * 64];
    __shared__ int sels[64 * 9];
    double* tile_d = (double*)smem;
    float* tileq = (float*)smem;
    int blk = blockIdx.x;
    int b = blk >> 6, i = blk & 63;
    int t = threadIdx.x;
    int lane = t & 63, wv = t >> 6;

    for (int p = t; p < 64 * 50; p += 512) dotsd[p] = 0.0;
    for (int p = t; p < 448; p += 512) sqd[p] = 0.0;

    for (int q = 0; q < 16; ++q) {
        __syncthreads();
        for (int s = t; s < 896; s += 512) {
            int rc = s >> 5, c2 = s & 31;
            int r = rc >> 2, c = rc & 3;
            int gr = i - 3 + r;
            if (gr >= 0 && gr <= 63) {
                const double* src = x1hp(o, b * 64 + q * 4 + c);
                *(double2*)(tile_d + rc * 66 + c2 * 2) = *(const double2*)(src + gr * 64 + c2 * 2);
            }
        }
        __syncthreads();
        for (int p = t; p < 448; p += 512) {
            int r = p >> 6, col = p & 63;
            int gr = i - 3 + r;
            if (gr >= 0 && gr <= 63) {
                double s = 0.0;
                #pragma unroll
                for (int c = 0; c < 4; ++c) {
                    double xv = tile_d[(r * 4 + c) * 66 + col];
                    s = fma(xv, xv, s);
                }
                sqd[p] += s;
            }
        }
        double xlq[4];
        #pragma unroll
        for (int c = 0; c < 4; ++c) xlq[c] = tile_d[(12 + c) * 66 + lane];
        for (int oo = wv; oo < 49; oo += 8) {
            int oi = oo / 7 - 3, oj = oo % 7 - 3;
            int mi = i + oi, mj = lane + oj;
            if (mi >= 0 && mi <= 63 && mj >= 0 && mj <= 63) {
                int r = oi + 3;
                double dot = 0.0;
                #pragma unroll
                for (int c = 0; c < 4; ++c) dot = fma(xlq[c], tile_d[(r * 4 + c) * 66 + mj], dot);
                dotsd[lane * 50 + oo] += dot;
            }
        }
    }
    __syncthreads();
    for (int oo = wv; oo < 49; oo += 8) {
        int oi = oo / 7 - 3, oj = oo % 7 - 3;
        int mi = i + oi, mj = lane + oj;
        double d2 = -1e300;
        if (mi >= 0 && mi <= 63 && mj >= 0 && mj <= 63)
            d2 = sqd[192 + lane] + sqd[(oi + 3) * 64 + mj] - 2.0 * dotsd[lane * 50 + oo];
        dotsd[lane * 50 + oo] = d2;
    }
    __syncthreads();
    if (wv == 0) {
        unsigned long long mask = 0ull;
        for (int k = 0; k < 9; ++k) {
            double best = -1e308; int bi = 0;
            for (int oo = 0; oo < 49; ++oo) {
                if ((mask >> oo) & 1ull) continue;
                double vv = dotsd[lane * 50 + oo];
                if (vv > best) { best = vv; bi = oo; }
            }
            mask |= (1ull << bi);
            sels[lane * 9 + k] = bi;
        }
    }
    __syncthreads();
    int rk[9], cj[9];
    #pragma unroll
    for (int k = 0; k < 9; ++k) {
        int oo = sels[lane * 9 + k];
        rk[k] = oo / 7;
        cj[k] = lane + (oo % 7) - 3;
    }
    for (int q = 0; q < 8; ++q) {
        __syncthreads();
        for (int s = t; s < 896; s += 512) {
            int rc = s >> 4, x4 = s & 15;
            int r = rc >> 3, c = rc & 7;
            int gr = i - 3 + r;
            if (gr >= 0 && gr <= 63)
                *(float4*)(tileq + rc * 68 + x4 * 4) =
                    *(const float4*)(catp(o, b * 128 + q * 8 + c) + gr * 64 + x4 * 4);
        }
        __syncthreads();
        {
            int c = wv;
            float s = 0.f;
            #pragma unroll
            for (int k = 0; k < 9; ++k) s += tileq[(rk[k] * 8 + c) * 68 + cj[k]];
            float outv = s * (1.f / 9.f) - tileq[(24 + c) * 68 + lane];
            catp(o, b * 128 + 64 + q * 8 + c)[i * 64 + lane] = outv;
        }
    }
}

// ---------------- K3: 3x3 conv (128->64) + BN + ReLU, LDS-staged weights+inputs
// grid: 256 = B*64 rows; block 1024. LDS 49.5KB. 8 stages of 16 ci.
__global__ __launch_bounds__(1024) void k3_conv(
    float* __restrict__ o, const float* __restrict__ b1,
    const float* __restrict__ g, const float* __restrict__ be,
    const float* __restrict__ m, const float* __restrict__ v)
{
    __shared__ __align__(16) float wlds[16 * 9 * 64];
    __shared__ __align__(16) float xlds[3 * 16 * 72];
    int blk = blockIdx.x;
    int b = blk >> 6, i = blk & 63;
    int t = threadIdx.x;
    int co = t & 63, jg = t >> 6;
    float acc0 = 0.f, acc1 = 0.f, acc2 = 0.f, acc3 = 0.f;
    const float4 z4 = make_float4(0.f, 0.f, 0.f, 0.f);
    for (int st = 0; st < 8; ++st) {
        __syncthreads();
        for (int idx = t; idx < 9216; idx += 1024) {
            int kk = st * 144 + (idx >> 6);
            wlds[idx] = wtv(o, kk, idx & 63);
        }
        for (int f = t; f < 864; f += 1024) {
            int x4 = f % 18, rc = f / 18;
            int ry = rc >> 4, cl = rc & 15;
            int gr = i - 1 + ry;
            float4 val = z4;
            if (x4 >= 1 && x4 <= 16 && gr >= 0 && gr <= 63)
                val = *(const float4*)(catp(o, b * 128 + st * 16 + cl) + gr * 64 + (x4 - 1) * 4);
            *(float4*)(xlds + rc * 72 + x4 * 4) = val;
        }
        __syncthreads();
        for (int cl = 0; cl < 16; ++cl) {
            #pragma unroll
            for (int ry = 0; ry < 3; ++ry) {
                float w0  = wlds[(cl * 9 + ry * 3 + 0) * 64 + co];
                float w1f = wlds[(cl * 9 + ry * 3 + 1) * 64 + co];
                float w2  = wlds[(cl * 9 + ry * 3 + 2) * 64 + co];
                const float* xr = xlds + (ry * 16 + cl) * 72 + jg * 4;
                float4 q0 = *(const float4*)(xr);
                float4 q1 = *(const float4*)(xr + 4);
                float4 q2 = *(const float4*)(xr + 8);
                float xv[12] = { q0.x,q0.y,q0.z,q0.w, q1.x,q1.y,q1.z,q1.w, q2.x,q2.y,q2.z,q2.w };
                acc0 = fmaf(w0, xv[3], fmaf(w1f, xv[4], fmaf(w2, xv[5], acc0)));
                acc1 = fmaf(w0, xv[4], fmaf(w1f, xv[5], fmaf(w2, xv[6], acc1)));
                acc2 = fmaf(w0, xv[5], fmaf(w1f, xv[6], fmaf(w2, xv[7], acc2)));
                acc3 = fmaf(w0, xv[6], fmaf(w1f, xv[7], fmaf(w2, xv[8], acc3)));
            }
        }
    }
    float sc = g[co] * rsqrtf(v[co] + 1e-5f);
    float sh = b1[co] - m[co];
    float bb = be[co];
    float4 ov;
    ov.x = fmaxf(0.f, fmaf(acc0 + sh, sc, bb));
    ov.y = fmaxf(0.f, fmaf(acc1 + sh, sc, bb));
    ov.z = fmaxf(0.f, fmaf(acc2 + sh, sc, bb));
    ov.w = fmaxf(0.f, fmaf(acc3 + sh, sc, bb));
    *(float4*)(o + (size_t)(b * 64 + co) * 65536 + i * 64 + jg * 4) = ov;
}

// ---------------- K4a: per-plane spatial mean -> slot[12288]
__global__ __launch_bounds__(256) void k4_mean(float* __restrict__ o) {
    int q = blockIdx.x, t = threadIdx.x;
    const float* p = o + (size_t)q * 65536;
    float s = 0.f;
    for (int k = t; k < 4096; k += 256) s += p[k];
    #pragma unroll
    for (int off = 32; off > 0; off >>= 1) s += __shfl_down(s, off, 64);
    __shared__ float red[4];
    if ((t & 63) == 0) red[t >> 6] = s;
    __syncthreads();
    if (t == 0) o[(size_t)q * 65536 + 12288] = (red[0] + red[1] + red[2] + red[3]) * (1.f / 4096.f);
}

// ---------------- K4b: 1x1 conv + BN + sigmoid -> slot[12289]
__global__ __launch_bounds__(256) void k4_att(float* __restrict__ o, const float* __restrict__ wa,
    const float* __restrict__ g, const float* __restrict__ be, const float* __restrict__ m, const float* __restrict__ v) {
    int t = threadIdx.x;
    int b = t >> 6, co = t & 63;
    const float* wr = wa + co * 64;
    float s = 0.f;
    for (int ci = 0; ci < 64; ++ci) s = fmaf(wr[ci], o[(size_t)(b * 64 + ci) * 65536 + 12288], s);
    float sc = g[co] * rsqrtf(v[co] + 1e-5f);
    float y = fmaf(s - m[co], sc, be[co]);
    o[(size_t)t * 65536 + 12289] = 1.f / (1.f + expf(-y));
}

// ---------------- K5: out = bilinear_x4(feat)*att, in place over own slot. block 1024.
__global__ __launch_bounds__(1024) void k5_up(float* __restrict__ o) {
    __shared__ __align__(16) float fplane[4096];
    int bc = blockIdx.x;
    int t = threadIdx.x;
    float* slot = o + (size_t)bc * 65536;
    *(float4*)(fplane + t * 4) = *(const float4*)(slot + t * 4);
    float att = slot[12289];
    __syncthreads();
    int ox = t & 255, oyc = t >> 8;
    float fx = ox * 0.25f - 0.375f;
    int ix = (int)floorf(fx);
    float wx = fx - (float)ix;
    int x0 = ix < 0 ? 0 : ix;
    int x1 = (ix + 1 > 63) ? 63 : ix + 1;
    for (int oy = oyc * 64; oy < oyc * 64 + 64; ++oy) {
        float fy = oy * 0.25f - 0.375f;
        int iy = (int)floorf(fy);
        float wy = fy - (float)iy;
        int y0 = iy < 0 ? 0 : iy;
        int y1 = (iy + 1 > 63) ? 63 : iy + 1;
        float a  = fplane[y0 * 64 + x0], b_ = fplane[y0 * 64 + x1];
        float c_ = fplane[y1 * 64 + x0], d_ = fplane[y1 * 64 + x1];
        float top = a + wx * (b_ - a);
        float bot = c_ + wx * (d_ - c_);
        float val = (top + wy * (bot - top)) * att;
        slot[oy * 256 + ox] = val;
    }
}

extern "C" void kernel_launch(void* const* d_in, const int* in_sizes, int n_in,
                              void* d_out, int out_size, void* d_ws, size_t ws_size,
                              hipStream_t stream) {
    const float* x     = (const float*)d_in[0];
    const float* wd    = (const float*)d_in[1];
    const float* bd    = (const float*)d_in[2];
    const float* bnd_g = (const float*)d_in[3];
    const float* bnd_b = (const float*)d_in[4];
    const float* bnd_m = (const float*)d_in[5];
    const float* bnd_v = (const float*)d_in[6];
    const float* w1    = (const float*)d_in[7];
    const float* b1    = (const float*)d_in[8];
    const float* bn1_g = (const float*)d_in[9];
    const float* bn1_b = (const float*)d_in[10];
    const float* bn1_m = (const float*)d_in[11];
    const float* bn1_v = (const float*)d_in[12];
    const float* wa    = (const float*)d_in[13];
    const float* bna_g = (const float*)d_in[14];
    const float* bna_b = (const float*)d_in[15];
    const float* bna_m = (const float*)d_in[16];
    const float* bna_v = (const float*)d_in[17];

    float* o = (float*)d_out;

    hipLaunchKernelGGL(k0_wtrans, dim3(288), dim3(256), 0, stream, w1, o);
    hipLaunchKernelGGL(k1_convds, dim3(512), dim3(256), 0, stream,
                       x, wd, bd, bnd_g, bnd_b, bnd_m, bnd_v, o);
    hipLaunchKernelGGL(k2_feat, dim3(256), dim3(512), 0, stream, o);
    hipLaunchKernelGGL(k3_conv, dim3(256), dim3(1024), 0, stream,
                       o, b1, bn1_g, bn1_b, bn1_m, bn1_v);
    hipLaunchKernelGGL(k4_mean, dim3(256), dim3(256), 0, stream, o);
    hipLaunchKernelGGL(k4_att, dim3(1), dim3(256), 0, stream,
                       o, wa, bna_g, bna_b, bna_m, bna_v);
    hipLaunchKernelGGL(k5_up, dim3(256), dim3(1024), 0, stream, o);
}

// Round 16
// 259.480 us; speedup vs baseline: 1.3461x; 1.1343x over previous
//
#include <hip/hip_runtime.h>
#include <hip/hip_bf16.h>
#include <stdint.h>

// ---- All intermediates live inside d_out (16,777,216 f32; 256 slots x 65536 f32).
// Slot q (q=b*64+co): [0,4096) feat plane q ; [4096,8192) cat plane p (p<256, p&255==q)
// [8192,12288) cat plane p (p>=256) ; [12288] mean ; [12289] att ;
// [16384,24576) f64 x1_hi plane q ; [25600,26112) wT chunks ; [26624,27136) wdT64 chunks (f64).
__device__ __forceinline__ float* catp(float* o, int p) {
    return o + (size_t)(p & 255) * 65536 + 4096 + ((p >> 8) << 12);
}
__device__ __forceinline__ double* x1hp(float* o, int q) {
    return (double*)(o + (size_t)q * 65536 + 16384);
}
__device__ __forceinline__ float wtv(const float* o, int kk, int co) {
    return o[(size_t)(kk >> 3) * 65536 + 25600 + (kk & 7) * 64 + co];
}
__device__ __forceinline__ double* wd64p(float* o, int k) {   // + co
    return (double*)(o + (size_t)(k >> 2) * 65536 + 26624) + (k & 3) * 64;
}

// ---------------- K0: w1 -> wT[kk][co] (f32); wd -> wdT64[k][co] (f64)
__global__ __launch_bounds__(256) void k0_wtrans(const float* __restrict__ w1, const float* __restrict__ wd,
                                                 float* __restrict__ o) {
    int idx = blockIdx.x * 256 + threadIdx.x;
    if (idx < 73728) {
        int co = idx & 63, kk = idx >> 6;
        o[(size_t)(kk >> 3) * 65536 + 25600 + (kk & 7) * 64 + co] = w1[co * 1152 + kk];
    } else if (idx < 139264) {
        int j = idx - 73728;
        int co = j & 63, k = j >> 6;
        wd64p(o, k)[co] = (double)wd[co * 1024 + k];
    }
}

// ---------------- K1: 4x4/stride-4 conv + BN + ReLU as f64 register-blocked GEMM
// grid: 256 = (b,i); block 256; thread = 4co x 4j micro-tile. 32 panels of K=32.
// LDS 32KB: wlds[32k][64co] f64 + xlds[32k][64j] f64.
__global__ __launch_bounds__(256) void k1_convds(
    const float* __restrict__ x, const float* __restrict__ bd,
    const float* __restrict__ g, const float* __restrict__ be,
    const float* __restrict__ m, const float* __restrict__ v,
    float* __restrict__ o)
{
    __shared__ __align__(16) double wlds[32 * 64];
    __shared__ __align__(16) double xlds[32 * 64];
    int blk = blockIdx.x;
    int b = blk >> 6, i = blk & 63;
    int t = threadIdx.x;
    int tj = t & 15, tc = t >> 4;
    int j0 = tj * 4, co0 = tc * 4;
    double acc[4][4];
    #pragma unroll
    for (int c = 0; c < 4; ++c)
        #pragma unroll
        for (int jj = 0; jj < 4; ++jj) acc[c][jj] = 0.0;
    for (int p = 0; p < 32; ++p) {
        __syncthreads();
        // stage W panel: 32k x 64co f64, coalesced from wdT64
        #pragma unroll
        for (int u = 0; u < 8; ++u) {
            int idx = t + u * 256;
            int kl = idx >> 6, co = idx & 63;
            wlds[kl * 64 + co] = wd64p(o, p * 32 + kl)[co];
        }
        // stage X panel: 2ci x 4ky x 256cols f32 -> [k][j] f64 (kx transposed into k)
        #pragma unroll
        for (int u = 0; u < 2; ++u) {
            int idx = t + u * 256;
            int f4j = idx & 63, ky = (idx >> 6) & 3, ciL = idx >> 8;
            const float* src = x + (((size_t)(b * 64 + p * 2 + ciL) * 256 + (i * 4 + ky)) * 256 + f4j * 4);
            float4 f = *(const float4*)src;
            int kq = (ciL * 16 + ky * 4) * 64 + f4j;
            xlds[kq]       = (double)f.x;
            xlds[kq + 64]  = (double)f.y;
            xlds[kq + 128] = (double)f.z;
            xlds[kq + 192] = (double)f.w;
        }
        __syncthreads();
        #pragma unroll
        for (int ciL = 0; ciL < 2; ++ciL) {
            #pragma unroll
            for (int ky = 0; ky < 4; ++ky) {
                int kq = ciL * 16 + ky * 4;
                double w_[4][4], x_[4][4];
                #pragma unroll
                for (int kx = 0; kx < 4; ++kx) {
                    const double* wp = wlds + (kq + kx) * 64 + co0;
                    const double* xp = xlds + (kq + kx) * 64 + j0;
                    w_[kx][0] = wp[0]; w_[kx][1] = wp[1]; w_[kx][2] = wp[2]; w_[kx][3] = wp[3];
                    x_[kx][0] = xp[0]; x_[kx][1] = xp[1]; x_[kx][2] = xp[2]; x_[kx][3] = xp[3];
                }
                #pragma unroll
                for (int c = 0; c < 4; ++c)
                    #pragma unroll
                    for (int jj = 0; jj < 4; ++jj)
                        acc[c][jj] = fma(w_[0][c], x_[0][jj],
                                     fma(w_[1][c], x_[1][jj],
                                     fma(w_[2][c], x_[2][jj],
                                     fma(w_[3][c], x_[3][jj], acc[c][jj]))));
            }
        }
    }
    #pragma unroll
    for (int c = 0; c < 4; ++c) {
        int co = co0 + c;
        double sc = (double)g[co] / sqrt((double)v[co] + 1e-5);
        double sh = (double)bd[co] - (double)m[co];
        double bb = (double)be[co];
        double o0v = fmax(0.0, (acc[c][0] + sh) * sc + bb);
        double o1v = fmax(0.0, (acc[c][1] + sh) * sc + bb);
        double o2v = fmax(0.0, (acc[c][2] + sh) * sc + bb);
        double o3v = fmax(0.0, (acc[c][3] + sh) * sc + bb);
        int pos = i * 64 + j0;
        float4 ov;
        ov.x = (float)o0v; ov.y = (float)o1v; ov.z = (float)o2v; ov.w = (float)o3v;
        *(float4*)(catp(o, b * 128 + co) + pos) = ov;
        double* xh = x1hp(o, b * 64 + co);
        *(double2*)(xh + pos)     = make_double2(o0v, o1v);
        *(double2*)(xh + pos + 2) = make_double2(o2v, o3v);
    }
}

// ---------------- K2: windowed d^2 (f64) -> top-9 -> f32 neighbor-mean diff. block 512.
__global__ __launch_bounds__(512) void k2_feat(float* __restrict__ o)
{
    __shared__ __align__(16) char smem[15232];
    __shared__ double dotsd[64 * 50];
    __shared__ double sqd[7 * 64];
    __shared__ int sels[64 * 9];
    double* tile_d = (double*)smem;
    float* tileq = (float*)smem;
    int blk = blockIdx.x;
    int b = blk >> 6, i = blk & 63;
    int t = threadIdx.x;
    int lane = t & 63, wv = t >> 6;

    for (int p = t; p < 64 * 50; p += 512) dotsd[p] = 0.0;
    for (int p = t; p < 448; p += 512) sqd[p] = 0.0;

    for (int q = 0; q < 16; ++q) {
        __syncthreads();
        for (int s = t; s < 896; s += 512) {
            int rc = s >> 5, c2 = s & 31;
            int r = rc >> 2, c = rc & 3;
            int gr = i - 3 + r;
            if (gr >= 0 && gr <= 63) {
                const double* src = x1hp(o, b * 64 + q * 4 + c);
                *(double2*)(tile_d + rc * 66 + c2 * 2) = *(const double2*)(src + gr * 64 + c2 * 2);
            }
        }
        __syncthreads();
        for (int p = t; p < 448; p += 512) {
            int r = p >> 6, col = p & 63;
            int gr = i - 3 + r;
            if (gr >= 0 && gr <= 63) {
                double s = 0.0;
                #pragma unroll
                for (int c = 0; c < 4; ++c) {
                    double xv = tile_d[(r * 4 + c) * 66 + col];
                    s = fma(xv, xv, s);
                }
                sqd[p] += s;
            }
        }
        double xlq[4];
        #pragma unroll
        for (int c = 0; c < 4; ++c) xlq[c] = tile_d[(12 + c) * 66 + lane];
        for (int oo = wv; oo < 49; oo += 8) {
            int oi = oo / 7 - 3, oj = oo % 7 - 3;
            int mi = i + oi, mj = lane + oj;
            if (mi >= 0 && mi <= 63 && mj >= 0 && mj <= 63) {
                int r = oi + 3;
                double dot = 0.0;
                #pragma unroll
                for (int c = 0; c < 4; ++c) dot = fma(xlq[c], tile_d[(r * 4 + c) * 66 + mj], dot);
                dotsd[lane * 50 + oo] += dot;
            }
        }
    }
    __syncthreads();
    for (int oo = wv; oo < 49; oo += 8) {
        int oi = oo / 7 - 3, oj = oo % 7 - 3;
        int mi = i + oi, mj = lane + oj;
        double d2 = -1e300;
        if (mi >= 0 && mi <= 63 && mj >= 0 && mj <= 63)
            d2 = sqd[192 + lane] + sqd[(oi + 3) * 64 + mj] - 2.0 * dotsd[lane * 50 + oo];
        dotsd[lane * 50 + oo] = d2;
    }
    __syncthreads();
    if (wv == 0) {
        unsigned long long mask = 0ull;
        for (int k = 0; k < 9; ++k) {
            double best = -1e308; int bi = 0;
            for (int oo = 0; oo < 49; ++oo) {
                if ((mask >> oo) & 1ull) continue;
                double vv = dotsd[lane * 50 + oo];
                if (vv > best) { best = vv; bi = oo; }
            }
            mask |= (1ull << bi);
            sels[lane * 9 + k] = bi;
        }
    }
    __syncthreads();
    int rk[9], cj[9];
    #pragma unroll
    for (int k = 0; k < 9; ++k) {
        int oo = sels[lane * 9 + k];
        rk[k] = oo / 7;
        cj[k] = lane + (oo % 7) - 3;
    }
    for (int q = 0; q < 8; ++q) {
        __syncthreads();
        for (int s = t; s < 896; s += 512) {
            int rc = s >> 4, x4 = s & 15;
            int r = rc >> 3, c = rc & 7;
            int gr = i - 3 + r;
            if (gr >= 0 && gr <= 63)
                *(float4*)(tileq + rc * 68 + x4 * 4) =
                    *(const float4*)(catp(o, b * 128 + q * 8 + c) + gr * 64 + x4 * 4);
        }
        __syncthreads();
        {
            int c = wv;
            float s = 0.f;
            #pragma unroll
            for (int k = 0; k < 9; ++k) s += tileq[(rk[k] * 8 + c) * 68 + cj[k]];
            float outv = s * (1.f / 9.f) - tileq[(24 + c) * 68 + lane];
            catp(o, b * 128 + 64 + q * 8 + c)[i * 64 + lane] = outv;
        }
    }
}

// ---------------- K3: 3x3 conv (128->64) + BN + ReLU, LDS-staged weights+inputs
// grid: 256 = B*64 rows; block 1024. LDS 49.5KB. 8 stages of 16 ci.
__global__ __launch_bounds__(1024) void k3_conv(
    float* __restrict__ o, const float* __restrict__ b1,
    const float* __restrict__ g, const float* __restrict__ be,
    const float* __restrict__ m, const float* __restrict__ v)
{
    __shared__ __align__(16) float wlds[16 * 9 * 64];
    __shared__ __align__(16) float xlds[3 * 16 * 72];
    int blk = blockIdx.x;
    int b = blk >> 6, i = blk & 63;
    int t = threadIdx.x;
    int co = t & 63, jg = t >> 6;
    float acc0 = 0.f, acc1 = 0.f, acc2 = 0.f, acc3 = 0.f;
    const float4 z4 = make_float4(0.f, 0.f, 0.f, 0.f);
    for (int st = 0; st < 8; ++st) {
        __syncthreads();
        for (int idx = t; idx < 9216; idx += 1024) {
            int kk = st * 144 + (idx >> 6);
            wlds[idx] = wtv(o, kk, idx & 63);
        }
        for (int f = t; f < 864; f += 1024) {
            int x4 = f % 18, rc = f / 18;
            int ry = rc >> 4, cl = rc & 15;
            int gr = i - 1 + ry;
            float4 val = z4;
            if (x4 >= 1 && x4 <= 16 && gr >= 0 && gr <= 63)
                val = *(const float4*)(catp(o, b * 128 + st * 16 + cl) + gr * 64 + (x4 - 1) * 4);
            *(float4*)(xlds + rc * 72 + x4 * 4) = val;
        }
        __syncthreads();
        for (int cl = 0; cl < 16; ++cl) {
            #pragma unroll
            for (int ry = 0; ry < 3; ++ry) {
                float w0  = wlds[(cl * 9 + ry * 3 + 0) * 64 + co];
                float w1f = wlds[(cl * 9 + ry * 3 + 1) * 64 + co];
                float w2  = wlds[(cl * 9 + ry * 3 + 2) * 64 + co];
                const float* xr = xlds + (ry * 16 + cl) * 72 + jg * 4;
                float4 q0 = *(const float4*)(xr);
                float4 q1 = *(const float4*)(xr + 4);
                float4 q2 = *(const float4*)(xr + 8);
                float xv[12] = { q0.x,q0.y,q0.z,q0.w, q1.x,q1.y,q1.z,q1.w, q2.x,q2.y,q2.z,q2.w };
                acc0 = fmaf(w0, xv[3], fmaf(w1f, xv[4], fmaf(w2, xv[5], acc0)));
                acc1 = fmaf(w0, xv[4], fmaf(w1f, xv[5], fmaf(w2, xv[6], acc1)));
                acc2 = fmaf(w0, xv[5], fmaf(w1f, xv[6], fmaf(w2, xv[7], acc2)));
                acc3 = fmaf(w0, xv[6], fmaf(w1f, xv[7], fmaf(w2, xv[8], acc3)));
            }
        }
    }
    float sc = g[co] * rsqrtf(v[co] + 1e-5f);
    float sh = b1[co] - m[co];
    float bb = be[co];
    float4 ov;
    ov.x = fmaxf(0.f, fmaf(acc0 + sh, sc, bb));
    ov.y = fmaxf(0.f, fmaf(acc1 + sh, sc, bb));
    ov.z = fmaxf(0.f, fmaf(acc2 + sh, sc, bb));
    ov.w = fmaxf(0.f, fmaf(acc3 + sh, sc, bb));
    *(float4*)(o + (size_t)(b * 64 + co) * 65536 + i * 64 + jg * 4) = ov;
}

// ---------------- K4a: per-plane spatial mean -> slot[12288]
__global__ __launch_bounds__(256) void k4_mean(float* __restrict__ o) {
    int q = blockIdx.x, t = threadIdx.x;
    const float* p = o + (size_t)q * 65536;
    float s = 0.f;
    for (int k = t; k < 4096; k += 256) s += p[k];
    #pragma unroll
    for (int off = 32; off > 0; off >>= 1) s += __shfl_down(s, off, 64);
    __shared__ float red[4];
    if ((t & 63) == 0) red[t >> 6] = s;
    __syncthreads();
    if (t == 0) o[(size_t)q * 65536 + 12288] = (red[0] + red[1] + red[2] + red[3]) * (1.f / 4096.f);
}

// ---------------- K4b: 1x1 conv + BN + sigmoid -> slot[12289]
__global__ __launch_bounds__(256) void k4_att(float* __restrict__ o, const float* __restrict__ wa,
    const float* __restrict__ g, const float* __restrict__ be, const float* __restrict__ m, const float* __restrict__ v) {
    int t = threadIdx.x;
    int b = t >> 6, co = t & 63;
    const float* wr = wa + co * 64;
    float s = 0.f;
    for (int ci = 0; ci < 64; ++ci) s = fmaf(wr[ci], o[(size_t)(b * 64 + ci) * 65536 + 12288], s);
    float sc = g[co] * rsqrtf(v[co] + 1e-5f);
    float y = fmaf(s - m[co], sc, be[co]);
    o[(size_t)t * 65536 + 12289] = 1.f / (1.f + expf(-y));
}

// ---------------- K5: out = bilinear_x4(feat)*att, in place over own slot. block 1024.
__global__ __launch_bounds__(1024) void k5_up(float* __restrict__ o) {
    __shared__ __align__(16) float fplane[4096];
    int bc = blockIdx.x;
    int t = threadIdx.x;
    float* slot = o + (size_t)bc * 65536;
    *(float4*)(fplane + t * 4) = *(const float4*)(slot + t * 4);
    float att = slot[12289];
    __syncthreads();
    int ox = t & 255, oyc = t >> 8;
    float fx = ox * 0.25f - 0.375f;
    int ix = (int)floorf(fx);
    float wx = fx - (float)ix;
    int x0 = ix < 0 ? 0 : ix;
    int x1 = (ix + 1 > 63) ? 63 : ix + 1;
    for (int oy = oyc * 64; oy < oyc * 64 + 64; ++oy) {
        float fy = oy * 0.25f - 0.375f;
        int iy = (int)floorf(fy);
        float wy = fy - (float)iy;
        int y0 = iy < 0 ? 0 : iy;
        int y1 = (iy + 1 > 63) ? 63 : iy + 1;
        float a  = fplane[y0 * 64 + x0], b_ = fplane[y0 * 64 + x1];
        float c_ = fplane[y1 * 64 + x0], d_ = fplane[y1 * 64 + x1];
        float top = a + wx * (b_ - a);
        float bot = c_ + wx * (d_ - c_);
        float val = (top + wy * (bot - top)) * att;
        slot[oy * 256 + ox] = val;
    }
}

extern "C" void kernel_launch(void* const* d_in, const int* in_sizes, int n_in,
                              void* d_out, int out_size, void* d_ws, size_t ws_size,
                              hipStream_t stream) {
    const float* x     = (const float*)d_in[0];
    const float* wd    = (const float*)d_in[1];
    const float* bd    = (const float*)d_in[2];
    const float* bnd_g = (const float*)d_in[3];
    const float* bnd_b = (const float*)d_in[4];
    const float* bnd_m = (const float*)d_in[5];
    const float* bnd_v = (const float*)d_in[6];
    const float* w1    = (const float*)d_in[7];
    const float* b1    = (const float*)d_in[8];
    const float* bn1_g = (const float*)d_in[9];
    const float* bn1_b = (const float*)d_in[10];
    const float* bn1_m = (const float*)d_in[11];
    const float* bn1_v = (const float*)d_in[12];
    const float* wa    = (const float*)d_in[13];
    const float* bna_g = (const float*)d_in[14];
    const float* bna_b = (const float*)d_in[15];
    const float* bna_m = (const float*)d_in[16];
    const float* bna_v = (const float*)d_in[17];

    float* o = (float*)d_out;

    hipLaunchKernelGGL(k0_wtrans, dim3(544), dim3(256), 0, stream, w1, wd, o);
    hipLaunchKernelGGL(k1_convds, dim3(256), dim3(256), 0, stream,
                       x, bd, bnd_g, bnd_b, bnd_m, bnd_v, o);
    hipLaunchKernelGGL(k2_feat, dim3(256), dim3(512), 0, stream, o);
    hipLaunchKernelGGL(k3_conv, dim3(256), dim3(1024), 0, stream,
                       o, b1, bn1_g, bn1_b, bn1_m, bn1_v);
    hipLaunchKernelGGL(k4_mean, dim3(256), dim3(256), 0, stream, o);
    hipLaunchKernelGGL(k4_att, dim3(1), dim3(256), 0, stream,
                       o, wa, bna_g, bna_b, bna_m, bna_v);
    hipLaunchKernelGGL(k5_up, dim3(256), dim3(1024), 0, stream, o);
}

// Round 17
// 256.589 us; speedup vs baseline: 1.3613x; 1.0113x over previous
//
#include <hip/hip_runtime.h>
#include <hip/hip_bf16.h>
#include <stdint.h>

// ---- All intermediates live inside d_out (16,777,216 f32; 256 slots x 65536 f32).
// Slot q (q=b*64+co): [0,4096) feat plane q ; [4096,8192) cat plane p (p<256, p&255==q)
// [8192,12288) cat plane p (p>=256) ; [12288] mean ; [12289] att ;
// [16384,24576) f64 x1_hi plane q ; [25600,26112) wT chunks ; [26624,27136) wdT64 chunks (f64).
__device__ __forceinline__ float* catp(float* o, int p) {
    return o + (size_t)(p & 255) * 65536 + 4096 + ((p >> 8) << 12);
}
__device__ __forceinline__ double* x1hp(float* o, int q) {
    return (double*)(o + (size_t)q * 65536 + 16384);
}
__device__ __forceinline__ float wtv(const float* o, int kk, int co) {
    return o[(size_t)(kk >> 3) * 65536 + 25600 + (kk & 7) * 64 + co];
}
__device__ __forceinline__ double* wd64p(float* o, int k) {   // + co
    return (double*)(o + (size_t)(k >> 2) * 65536 + 26624) + (k & 3) * 64;
}

// ---------------- K0: w1 -> wT[kk][co] (f32); wd -> wdT64[k][co] (f64)
__global__ __launch_bounds__(256) void k0_wtrans(const float* __restrict__ w1, const float* __restrict__ wd,
                                                 float* __restrict__ o) {
    int idx = blockIdx.x * 256 + threadIdx.x;
    if (idx < 73728) {
        int co = idx & 63, kk = idx >> 6;
        o[(size_t)(kk >> 3) * 65536 + 25600 + (kk & 7) * 64 + co] = w1[co * 1152 + kk];
    } else if (idx < 139264) {
        int j = idx - 73728;
        int co = j & 63, k = j >> 6;
        wd64p(o, k)[co] = (double)wd[co * 1024 + k];
    }
}

// ---------------- K1: 4x4/stride-4 conv + BN + ReLU as f64 register-blocked GEMM
// grid: 256 = (b,i); block 256; thread = paired-strided 4co x 4j micro-tile:
// co in {tc*2, tc*2+1, tc*2+32, tc*2+33}, j in {tj*2, tj*2+1, tj*2+32, tj*2+33}.
// All LDS reads are double2 at lane-stride 16B -> conflict-free. Bit-identical outputs.
__global__ __launch_bounds__(256) void k1_convds(
    const float* __restrict__ x, const float* __restrict__ bd,
    const float* __restrict__ g, const float* __restrict__ be,
    const float* __restrict__ m, const float* __restrict__ v,
    float* __restrict__ o)
{
    __shared__ __align__(16) double wlds[32 * 64];
    __shared__ __align__(16) double xlds[32 * 64];
    int blk = blockIdx.x;
    int b = blk >> 6, i = blk & 63;
    int t = threadIdx.x;
    int tj = t & 15, tc = t >> 4;
    double acc[4][4];   // [c][jj]
    #pragma unroll
    for (int c = 0; c < 4; ++c)
        #pragma unroll
        for (int jj = 0; jj < 4; ++jj) acc[c][jj] = 0.0;
    for (int p = 0; p < 32; ++p) {
        __syncthreads();
        // stage W panel: 32k x 64co f64, coalesced from wdT64
        #pragma unroll
        for (int u = 0; u < 8; ++u) {
            int idx = t + u * 256;
            int kl = idx >> 6, co = idx & 63;
            wlds[kl * 64 + co] = wd64p(o, p * 32 + kl)[co];
        }
        // stage X panel: 2ci x 4ky x 256cols f32 -> [k][j] f64 (kx transposed into k)
        #pragma unroll
        for (int u = 0; u < 2; ++u) {
            int idx = t + u * 256;
            int f4j = idx & 63, ky = (idx >> 6) & 3, ciL = idx >> 8;
            const float* src = x + (((size_t)(b * 64 + p * 2 + ciL) * 256 + (i * 4 + ky)) * 256 + f4j * 4);
            float4 f = *(const float4*)src;
            int kq = (ciL * 16 + ky * 4) * 64 + f4j;
            xlds[kq]       = (double)f.x;
            xlds[kq + 64]  = (double)f.y;
            xlds[kq + 128] = (double)f.z;
            xlds[kq + 192] = (double)f.w;
        }
        __syncthreads();
        #pragma unroll
        for (int ciL = 0; ciL < 2; ++ciL) {
            #pragma unroll
            for (int ky = 0; ky < 4; ++ky) {
                int kq = ciL * 16 + ky * 4;
                double w_[4][4], x_[4][4];   // [kx][c], [kx][jj]
                #pragma unroll
                for (int kx = 0; kx < 4; ++kx) {
                    const double* wp = wlds + (kq + kx) * 64;
                    const double* xp = xlds + (kq + kx) * 64;
                    double2 wa0 = *(const double2*)(wp + tc * 2);
                    double2 wa1 = *(const double2*)(wp + tc * 2 + 32);
                    double2 xa0 = *(const double2*)(xp + tj * 2);
                    double2 xa1 = *(const double2*)(xp + tj * 2 + 32);
                    w_[kx][0] = wa0.x; w_[kx][1] = wa0.y; w_[kx][2] = wa1.x; w_[kx][3] = wa1.y;
                    x_[kx][0] = xa0.x; x_[kx][1] = xa0.y; x_[kx][2] = xa1.x; x_[kx][3] = xa1.y;
                }
                #pragma unroll
                for (int c = 0; c < 4; ++c)
                    #pragma unroll
                    for (int jj = 0; jj < 4; ++jj)
                        acc[c][jj] = fma(w_[0][c], x_[0][jj],
                                     fma(w_[1][c], x_[1][jj],
                                     fma(w_[2][c], x_[2][jj],
                                     fma(w_[3][c], x_[3][jj], acc[c][jj]))));
            }
        }
    }
    #pragma unroll
    for (int c = 0; c < 4; ++c) {
        int co = ((c >> 1) << 5) + tc * 2 + (c & 1);
        double sc = (double)g[co] / sqrt((double)v[co] + 1e-5);
        double sh = (double)bd[co] - (double)m[co];
        double bb = (double)be[co];
        double o0v = fmax(0.0, (acc[c][0] + sh) * sc + bb);
        double o1v = fmax(0.0, (acc[c][1] + sh) * sc + bb);
        double o2v = fmax(0.0, (acc[c][2] + sh) * sc + bb);
        double o3v = fmax(0.0, (acc[c][3] + sh) * sc + bb);
        int pos0 = i * 64 + tj * 2;
        float* cp = catp(o, b * 128 + co);
        *(float2*)(cp + pos0)      = make_float2((float)o0v, (float)o1v);
        *(float2*)(cp + pos0 + 32) = make_float2((float)o2v, (float)o3v);
        double* xh = x1hp(o, b * 64 + co);
        *(double2*)(xh + pos0)      = make_double2(o0v, o1v);
        *(double2*)(xh + pos0 + 32) = make_double2(o2v, o3v);
    }
}

// ---------------- K2: windowed d^2 (f64) -> top-9 -> f32 neighbor-mean diff. block 512.
__global__ __launch_bounds__(512) void k2_feat(float* __restrict__ o)
{
    __shared__ __align__(16) char smem[15232];
    __shared__ double dotsd[64 * 50];
    __shared__ double sqd[7 * 64];
    __shared__ int sels[64 * 9];
    double* tile_d = (double*)smem;
    float* tileq = (float*)smem;
    int blk = blockIdx.x;
    int b = blk >> 6, i = blk & 63;
    int t = threadIdx.x;
    int lane = t & 63, wv = t >> 6;

    for (int p = t; p < 64 * 50; p += 512) dotsd[p] = 0.0;
    for (int p = t; p < 448; p += 512) sqd[p] = 0.0;

    for (int q = 0; q < 16; ++q) {
        __syncthreads();
        for (int s = t; s < 896; s += 512) {
            int rc = s >> 5, c2 = s & 31;
            int r = rc >> 2, c = rc & 3;
            int gr = i - 3 + r;
            if (gr >= 0 && gr <= 63) {
                const double* src = x1hp(o, b * 64 + q * 4 + c);
                *(double2*)(tile_d + rc * 66 + c2 * 2) = *(const double2*)(src + gr * 64 + c2 * 2);
            }
        }
        __syncthreads();
        for (int p = t; p < 448; p += 512) {
            int r = p >> 6, col = p & 63;
            int gr = i - 3 + r;
            if (gr >= 0 && gr <= 63) {
                double s = 0.0;
                #pragma unroll
                for (int c = 0; c < 4; ++c) {
                    double xv = tile_d[(r * 4 + c) * 66 + col];
                    s = fma(xv, xv, s);
                }
                sqd[p] += s;
            }
        }
        double xlq[4];
        #pragma unroll
        for (int c = 0; c < 4; ++c) xlq[c] = tile_d[(12 + c) * 66 + lane];
        for (int oo = wv; oo < 49; oo += 8) {
            int oi = oo / 7 - 3, oj = oo % 7 - 3;
            int mi = i + oi, mj = lane + oj;
            if (mi >= 0 && mi <= 63 && mj >= 0 && mj <= 63) {
                int r = oi + 3;
                double dot = 0.0;
                #pragma unroll
                for (int c = 0; c < 4; ++c) dot = fma(xlq[c], tile_d[(r * 4 + c) * 66 + mj], dot);
                dotsd[lane * 50 + oo] += dot;
            }
        }
    }
    __syncthreads();
    for (int oo = wv; oo < 49; oo += 8) {
        int oi = oo / 7 - 3, oj = oo % 7 - 3;
        int mi = i + oi, mj = lane + oj;
        double d2 = -1e300;
        if (mi >= 0 && mi <= 63 && mj >= 0 && mj <= 63)
            d2 = sqd[192 + lane] + sqd[(oi + 3) * 64 + mj] - 2.0 * dotsd[lane * 50 + oo];
        dotsd[lane * 50 + oo] = d2;
    }
    __syncthreads();
    if (wv == 0) {
        unsigned long long mask = 0ull;
        for (int k = 0; k < 9; ++k) {
            double best = -1e308; int bi = 0;
            for (int oo = 0; oo < 49; ++oo) {
                if ((mask >> oo) & 1ull) continue;
                double vv = dotsd[lane * 50 + oo];
                if (vv > best) { best = vv; bi = oo; }
            }
            mask |= (1ull << bi);
            sels[lane * 9 + k] = bi;
        }
    }
    __syncthreads();
    int rk[9], cj[9];
    #pragma unroll
    for (int k = 0; k < 9; ++k) {
        int oo = sels[lane * 9 + k];
        rk[k] = oo / 7;
        cj[k] = lane + (oo % 7) - 3;
    }
    for (int q = 0; q < 8; ++q) {
        __syncthreads();
        for (int s = t; s < 896; s += 512) {
            int rc = s >> 4, x4 = s & 15;
            int r = rc >> 3, c = rc & 7;
            int gr = i - 3 + r;
            if (gr >= 0 && gr <= 63)
                *(float4*)(tileq + rc * 68 + x4 * 4) =
                    *(const float4*)(catp(o, b * 128 + q * 8 + c) + gr * 64 + x4 * 4);
        }
        __syncthreads();
        {
            int c = wv;
            float s = 0.f;
            #pragma unroll
            for (int k = 0; k < 9; ++k) s += tileq[(rk[k] * 8 + c) * 68 + cj[k]];
            float outv = s * (1.f / 9.f) - tileq[(24 + c) * 68 + lane];
            catp(o, b * 128 + 64 + q * 8 + c)[i * 64 + lane] = outv;
        }
    }
}

// ---------------- K3: 3x3 conv (128->64) + BN + ReLU, LDS-staged weights+inputs
// grid: 256 = B*64 rows; block 1024. LDS 49.5KB. 8 stages of 16 ci.
__global__ __launch_bounds__(1024) void k3_conv(
    float* __restrict__ o, const float* __restrict__ b1,
    const float* __restrict__ g, const float* __restrict__ be,
    const float* __restrict__ m, const float* __restrict__ v)
{
    __shared__ __align__(16) float wlds[16 * 9 * 64];
    __shared__ __align__(16) float xlds[3 * 16 * 72];
    int blk = blockIdx.x;
    int b = blk >> 6, i = blk & 63;
    int t = threadIdx.x;
    int co = t & 63, jg = t >> 6;
    float acc0 = 0.f, acc1 = 0.f, acc2 = 0.f, acc3 = 0.f;
    const float4 z4 = make_float4(0.f, 0.f, 0.f, 0.f);
    for (int st = 0; st < 8; ++st) {
        __syncthreads();
        for (int idx = t; idx < 9216; idx += 1024) {
            int kk = st * 144 + (idx >> 6);
            wlds[idx] = wtv(o, kk, idx & 63);
        }
        for (int f = t; f < 864; f += 1024) {
            int x4 = f % 18, rc = f / 18;
            int ry = rc >> 4, cl = rc & 15;
            int gr = i - 1 + ry;
            float4 val = z4;
            if (x4 >= 1 && x4 <= 16 && gr >= 0 && gr <= 63)
                val = *(const float4*)(catp(o, b * 128 + st * 16 + cl) + gr * 64 + (x4 - 1) * 4);
            *(float4*)(xlds + rc * 72 + x4 * 4) = val;
        }
        __syncthreads();
        for (int cl = 0; cl < 16; ++cl) {
            #pragma unroll
            for (int ry = 0; ry < 3; ++ry) {
                float w0  = wlds[(cl * 9 + ry * 3 + 0) * 64 + co];
                float w1f = wlds[(cl * 9 + ry * 3 + 1) * 64 + co];
                float w2  = wlds[(cl * 9 + ry * 3 + 2) * 64 + co];
                const float* xr = xlds + (ry * 16 + cl) * 72 + jg * 4;
                float4 q0 = *(const float4*)(xr);
                float4 q1 = *(const float4*)(xr + 4);
                float4 q2 = *(const float4*)(xr + 8);
                float xv[12] = { q0.x,q0.y,q0.z,q0.w, q1.x,q1.y,q1.z,q1.w, q2.x,q2.y,q2.z,q2.w };
                acc0 = fmaf(w0, xv[3], fmaf(w1f, xv[4], fmaf(w2, xv[5], acc0)));
                acc1 = fmaf(w0, xv[4], fmaf(w1f, xv[5], fmaf(w2, xv[6], acc1)));
                acc2 = fmaf(w0, xv[5], fmaf(w1f, xv[6], fmaf(w2, xv[7], acc2)));
                acc3 = fmaf(w0, xv[6], fmaf(w1f, xv[7], fmaf(w2, xv[8], acc3)));
            }
        }
    }
    float sc = g[co] * rsqrtf(v[co] + 1e-5f);
    float sh = b1[co] - m[co];
    float bb = be[co];
    float4 ov;
    ov.x = fmaxf(0.f, fmaf(acc0 + sh, sc, bb));
    ov.y = fmaxf(0.f, fmaf(acc1 + sh, sc, bb));
    ov.z = fmaxf(0.f, fmaf(acc2 + sh, sc, bb));
    ov.w = fmaxf(0.f, fmaf(acc3 + sh, sc, bb));
    *(float4*)(o + (size_t)(b * 64 + co) * 65536 + i * 64 + jg * 4) = ov;
}

// ---------------- K4a: per-plane spatial mean -> slot[12288]
__global__ __launch_bounds__(256) void k4_mean(float* __restrict__ o) {
    int q = blockIdx.x, t = threadIdx.x;
    const float* p = o + (size_t)q * 65536;
    float s = 0.f;
    for (int k = t; k < 4096; k += 256) s += p[k];
    #pragma unroll
    for (int off = 32; off > 0; off >>= 1) s += __shfl_down(s, off, 64);
    __shared__ float red[4];
    if ((t & 63) == 0) red[t >> 6] = s;
    __syncthreads();
    if (t == 0) o[(size_t)q * 65536 + 12288] = (red[0] + red[1] + red[2] + red[3]) * (1.f / 4096.f);
}

// ---------------- K4b: 1x1 conv + BN + sigmoid -> slot[12289]
__global__ __launch_bounds__(256) void k4_att(float* __restrict__ o, const float* __restrict__ wa,
    const float* __restrict__ g, const float* __restrict__ be, const float* __restrict__ m, const float* __restrict__ v) {
    int t = threadIdx.x;
    int b = t >> 6, co = t & 63;
    const float* wr = wa + co * 64;
    float s = 0.f;
    for (int ci = 0; ci < 64; ++ci) s = fmaf(wr[ci], o[(size_t)(b * 64 + ci) * 65536 + 12288], s);
    float sc = g[co] * rsqrtf(v[co] + 1e-5f);
    float y = fmaf(s - m[co], sc, be[co]);
    o[(size_t)t * 65536 + 12289] = 1.f / (1.f + expf(-y));
}

// ---------------- K5: out = bilinear_x4(feat)*att, in place over own slot. block 1024.
__global__ __launch_bounds__(1024) void k5_up(float* __restrict__ o) {
    __shared__ __align__(16) float fplane[4096];
    int bc = blockIdx.x;
    int t = threadIdx.x;
    float* slot = o + (size_t)bc * 65536;
    *(float4*)(fplane + t * 4) = *(const float4*)(slot + t * 4);
    float att = slot[12289];
    __syncthreads();
    int ox = t & 255, oyc = t >> 8;
    float fx = ox * 0.25f - 0.375f;
    int ix = (int)floorf(fx);
    float wx = fx - (float)ix;
    int x0 = ix < 0 ? 0 : ix;
    int x1 = (ix + 1 > 63) ? 63 : ix + 1;
    for (int oy = oyc * 64; oy < oyc * 64 + 64; ++oy) {
        float fy = oy * 0.25f - 0.375f;
        int iy = (int)floorf(fy);
        float wy = fy - (float)iy;
        int y0 = iy < 0 ? 0 : iy;
        int y1 = (iy + 1 > 63) ? 63 : iy + 1;
        float a  = fplane[y0 * 64 + x0], b_ = fplane[y0 * 64 + x1];
        float c_ = fplane[y1 * 64 + x0], d_ = fplane[y1 * 64 + x1];
        float top = a + wx * (b_ - a);
        float bot = c_ + wx * (d_ - c_);
        float val = (top + wy * (bot - top)) * att;
        slot[oy * 256 + ox] = val;
    }
}

extern "C" void kernel_launch(void* const* d_in, const int* in_sizes, int n_in,
                              void* d_out, int out_size, void* d_ws, size_t ws_size,
                              hipStream_t stream) {
    const float* x     = (const float*)d_in[0];
    const float* wd    = (const float*)d_in[1];
    const float* bd    = (const float*)d_in[2];
    const float* bnd_g = (const float*)d_in[3];
    const float* bnd_b = (const float*)d_in[4];
    const float* bnd_m = (const float*)d_in[5];
    const float* bnd_v = (const float*)d_in[6];
    const float* w1    = (const float*)d_in[7];
    const float* b1    = (const float*)d_in[8];
    const float* bn1_g = (const float*)d_in[9];
    const float* bn1_b = (const float*)d_in[10];
    const float* bn1_m = (const float*)d_in[11];
    const float* bn1_v = (const float*)d_in[12];
    const float* wa    = (const float*)d_in[13];
    const float* bna_g = (const float*)d_in[14];
    const float* bna_b = (const float*)d_in[15];
    const float* bna_m = (const float*)d_in[16];
    const float* bna_v = (const float*)d_in[17];

    float* o = (float*)d_out;

    hipLaunchKernelGGL(k0_wtrans, dim3(544), dim3(256), 0, stream, w1, wd, o);
    hipLaunchKernelGGL(k1_convds, dim3(256), dim3(256), 0, stream,
                       x, bd, bnd_g, bnd_b, bnd_m, bnd_v, o);
    hipLaunchKernelGGL(k2_feat, dim3(256), dim3(512), 0, stream, o);
    hipLaunchKernelGGL(k3_conv, dim3(256), dim3(1024), 0, stream,
                       o, b1, bn1_g, bn1_b, bn1_m, bn1_v);
    hipLaunchKernelGGL(k4_mean, dim3(256), dim3(256), 0, stream, o);
    hipLaunchKernelGGL(k4_att, dim3(1), dim3(256), 0, stream,
                       o, wa, bna_g, bna_b, bna_m, bna_v);
    hipLaunchKernelGGL(k5_up, dim3(256), dim3(1024), 0, stream, o);
}

// Round 18
// 249.130 us; speedup vs baseline: 1.4020x; 1.0299x over previous
//
#include <hip/hip_runtime.h>
#include <hip/hip_bf16.h>
#include <stdint.h>

// ---- All intermediates live inside d_out (16,777,216 f32; 256 slots x 65536 f32).
// Slot q (q=b*64+co): [0,4096) feat plane q ; [4096,8192) cat plane p (p<256, p&255==q)
// [8192,12288) cat plane p (p>=256) ; [12288] mean ; [12289] att ;
// [16384,24576) f64 x1_hi plane q ; [25600,26112) wT chunks ; [26624,27136) wdT64 chunks (f64).
__device__ __forceinline__ float* catp(float* o, int p) {
    return o + (size_t)(p & 255) * 65536 + 4096 + ((p >> 8) << 12);
}
__device__ __forceinline__ double* x1hp(float* o, int q) {
    return (double*)(o + (size_t)q * 65536 + 16384);
}
__device__ __forceinline__ float wtv(const float* o, int kk, int co) {
    return o[(size_t)(kk >> 3) * 65536 + 25600 + (kk & 7) * 64 + co];
}
__device__ __forceinline__ double* wd64p(float* o, int k) {   // + co
    return (double*)(o + (size_t)(k >> 2) * 65536 + 26624) + (k & 3) * 64;
}

// ---------------- K0: w1 -> wT[kk][co] (f32); wd -> wdT64[k][co] (f64)
__global__ __launch_bounds__(256) void k0_wtrans(const float* __restrict__ w1, const float* __restrict__ wd,
                                                 float* __restrict__ o) {
    int idx = blockIdx.x * 256 + threadIdx.x;
    if (idx < 73728) {
        int co = idx & 63, kk = idx >> 6;
        o[(size_t)(kk >> 3) * 65536 + 25600 + (kk & 7) * 64 + co] = w1[co * 1152 + kk];
    } else if (idx < 139264) {
        int j = idx - 73728;
        int co = j & 63, k = j >> 6;
        wd64p(o, k)[co] = (double)wd[co * 1024 + k];
    }
}

// ---------------- K1: 4x4/stride-4 conv + BN + ReLU as f64 register-blocked GEMM
// grid: 512 = (b,i,jh); block 256; thread = 4co x 2j micro-tile:
// co in {tc*2, tc*2+1, tc*2+32, tc*2+33}, j = jh*32 + {tj*2, tj*2+1}.
// LDS 24KB (2 blocks/CU resident -> 8 waves/CU). Bit-identical outputs.
__global__ __launch_bounds__(256) void k1_convds(
    const float* __restrict__ x, const float* __restrict__ bd,
    const float* __restrict__ g, const float* __restrict__ be,
    const float* __restrict__ m, const float* __restrict__ v,
    float* __restrict__ o)
{
    __shared__ __align__(16) double wlds[32 * 64];   // 16KB
    __shared__ __align__(16) double xlds[32 * 32];   // 8KB
    int blk = blockIdx.x;
    int jh = blk & 1, i = (blk >> 1) & 63, b = blk >> 7;
    int t = threadIdx.x;
    int tj = t & 15, tc = t >> 4;   // tj 0..15 (j-pairs), tc 0..15 (co-pairs x2)
    double acc[4][2];   // [c][jj]
    #pragma unroll
    for (int c = 0; c < 4; ++c) { acc[c][0] = 0.0; acc[c][1] = 0.0; }
    for (int p = 0; p < 32; ++p) {
        __syncthreads();
        // stage W panel: 32k x 64co f64, coalesced from wdT64
        #pragma unroll
        for (int u = 0; u < 8; ++u) {
            int idx = t + u * 256;
            int kl = idx >> 6, co = idx & 63;
            wlds[kl * 64 + co] = wd64p(o, p * 32 + kl)[co];
        }
        // stage X half-panel: 2ci x 4ky x 32 f4-chunks (cols jh*128..jh*128+127)
        {
            int f4j = t & 31, ky = (t >> 5) & 3, ciL = t >> 7;
            const float* src = x + (((size_t)(b * 64 + p * 2 + ciL) * 256 + (i * 4 + ky)) * 256 + jh * 128 + f4j * 4);
            float4 f = *(const float4*)src;
            int kq = (ciL * 16 + ky * 4) * 32 + f4j;
            xlds[kq]      = (double)f.x;
            xlds[kq + 32] = (double)f.y;
            xlds[kq + 64] = (double)f.z;
            xlds[kq + 96] = (double)f.w;
        }
        __syncthreads();
        #pragma unroll
        for (int ciL = 0; ciL < 2; ++ciL) {
            #pragma unroll
            for (int ky = 0; ky < 4; ++ky) {
                int kq = ciL * 16 + ky * 4;
                double w_[4][4], x_[4][2];   // [kx][c], [kx][jj]
                #pragma unroll
                for (int kx = 0; kx < 4; ++kx) {
                    const double* wp = wlds + (kq + kx) * 64;
                    const double* xp = xlds + (kq + kx) * 32;
                    double2 wa0 = *(const double2*)(wp + tc * 2);
                    double2 wa1 = *(const double2*)(wp + tc * 2 + 32);
                    double2 xa0 = *(const double2*)(xp + tj * 2);
                    w_[kx][0] = wa0.x; w_[kx][1] = wa0.y; w_[kx][2] = wa1.x; w_[kx][3] = wa1.y;
                    x_[kx][0] = xa0.x; x_[kx][1] = xa0.y;
                }
                #pragma unroll
                for (int c = 0; c < 4; ++c)
                    #pragma unroll
                    for (int jj = 0; jj < 2; ++jj)
                        acc[c][jj] = fma(w_[0][c], x_[0][jj],
                                     fma(w_[1][c], x_[1][jj],
                                     fma(w_[2][c], x_[2][jj],
                                     fma(w_[3][c], x_[3][jj], acc[c][jj]))));
            }
        }
    }
    #pragma unroll
    for (int c = 0; c < 4; ++c) {
        int co = ((c >> 1) << 5) + tc * 2 + (c & 1);
        double sc = (double)g[co] / sqrt((double)v[co] + 1e-5);
        double sh = (double)bd[co] - (double)m[co];
        double bb = (double)be[co];
        double o0v = fmax(0.0, (acc[c][0] + sh) * sc + bb);
        double o1v = fmax(0.0, (acc[c][1] + sh) * sc + bb);
        int pos0 = i * 64 + jh * 32 + tj * 2;
        float* cp = catp(o, b * 128 + co);
        *(float2*)(cp + pos0) = make_float2((float)o0v, (float)o1v);
        double* xh = x1hp(o, b * 64 + co);
        *(double2*)(xh + pos0) = make_double2(o0v, o1v);
    }
}

// ---------------- K2: windowed d^2 (f64) -> top-9 -> f32 neighbor-mean diff. block 512.
__global__ __launch_bounds__(512) void k2_feat(float* __restrict__ o)
{
    __shared__ __align__(16) char smem[15232];
    __shared__ double dotsd[64 * 50];
    __shared__ double sqd[7 * 64];
    __shared__ int sels[64 * 9];
    double* tile_d = (double*)smem;
    float* tileq = (float*)smem;
    int blk = blockIdx.x;
    int b = blk >> 6, i = blk & 63;
    int t = threadIdx.x;
    int lane = t & 63, wv = t >> 6;

    for (int p = t; p < 64 * 50; p += 512) dotsd[p] = 0.0;
    for (int p = t; p < 448; p += 512) sqd[p] = 0.0;

    for (int q = 0; q < 16; ++q) {
        __syncthreads();
        for (int s = t; s < 896; s += 512) {
            int rc = s >> 5, c2 = s & 31;
            int r = rc >> 2, c = rc & 3;
            int gr = i - 3 + r;
            if (gr >= 0 && gr <= 63) {
                const double* src = x1hp(o, b * 64 + q * 4 + c);
                *(double2*)(tile_d + rc * 66 + c2 * 2) = *(const double2*)(src + gr * 64 + c2 * 2);
            }
        }
        __syncthreads();
        for (int p = t; p < 448; p += 512) {
            int r = p >> 6, col = p & 63;
            int gr = i - 3 + r;
            if (gr >= 0 && gr <= 63) {
                double s = 0.0;
                #pragma unroll
                for (int c = 0; c < 4; ++c) {
                    double xv = tile_d[(r * 4 + c) * 66 + col];
                    s = fma(xv, xv, s);
                }
                sqd[p] += s;
            }
        }
        double xlq[4];
        #pragma unroll
        for (int c = 0; c < 4; ++c) xlq[c] = tile_d[(12 + c) * 66 + lane];
        for (int oo = wv; oo < 49; oo += 8) {
            int oi = oo / 7 - 3, oj = oo % 7 - 3;
            int mi = i + oi, mj = lane + oj;
            if (mi >= 0 && mi <= 63 && mj >= 0 && mj <= 63) {
                int r = oi + 3;
                double dot = 0.0;
                #pragma unroll
                for (int c = 0; c < 4; ++c) dot = fma(xlq[c], tile_d[(r * 4 + c) * 66 + mj], dot);
                dotsd[lane * 50 + oo] += dot;
            }
        }
    }
    __syncthreads();
    for (int oo = wv; oo < 49; oo += 8) {
        int oi = oo / 7 - 3, oj = oo % 7 - 3;
        int mi = i + oi, mj = lane + oj;
        double d2 = -1e300;
        if (mi >= 0 && mi <= 63 && mj >= 0 && mj <= 63)
            d2 = sqd[192 + lane] + sqd[(oi + 3) * 64 + mj] - 2.0 * dotsd[lane * 50 + oo];
        dotsd[lane * 50 + oo] = d2;
    }
    __syncthreads();
    if (wv == 0) {
        unsigned long long mask = 0ull;
        for (int k = 0; k < 9; ++k) {
            double best = -1e308; int bi = 0;
            for (int oo = 0; oo < 49; ++oo) {
                if ((mask >> oo) & 1ull) continue;
                double vv = dotsd[lane * 50 + oo];
                if (vv > best) { best = vv; bi = oo; }
            }
            mask |= (1ull << bi);
            sels[lane * 9 + k] = bi;
        }
    }
    __syncthreads();
    int rk[9], cj[9];
    #pragma unroll
    for (int k = 0; k < 9; ++k) {
        int oo = sels[lane * 9 + k];
        rk[k] = oo / 7;
        cj[k] = lane + (oo % 7) - 3;
    }
    for (int q = 0; q < 8; ++q) {
        __syncthreads();
        for (int s = t; s < 896; s += 512) {
            int rc = s >> 4, x4 = s & 15;
            int r = rc >> 3, c = rc & 7;
            int gr = i - 3 + r;
            if (gr >= 0 && gr <= 63)
                *(float4*)(tileq + rc * 68 + x4 * 4) =
                    *(const float4*)(catp(o, b * 128 + q * 8 + c) + gr * 64 + x4 * 4);
        }
        __syncthreads();
        {
            int c = wv;
            float s = 0.f;
            #pragma unroll
            for (int k = 0; k < 9; ++k) s += tileq[(rk[k] * 8 + c) * 68 + cj[k]];
            float outv = s * (1.f / 9.f) - tileq[(24 + c) * 68 + lane];
            catp(o, b * 128 + 64 + q * 8 + c)[i * 64 + lane] = outv;
        }
    }
}

// ---------------- K3: 3x3 conv (128->64) + BN + ReLU, LDS-staged weights+inputs
// grid: 256 = B*64 rows; block 1024. LDS 49.5KB. 8 stages of 16 ci.
__global__ __launch_bounds__(1024) void k3_conv(
    float* __restrict__ o, const float* __restrict__ b1,
    const float* __restrict__ g, const float* __restrict__ be,
    const float* __restrict__ m, const float* __restrict__ v)
{
    __shared__ __align__(16) float wlds[16 * 9 * 64];
    __shared__ __align__(16) float xlds[3 * 16 * 72];
    int blk = blockIdx.x;
    int b = blk >> 6, i = blk & 63;
    int t = threadIdx.x;
    int co = t & 63, jg = t >> 6;
    float acc0 = 0.f, acc1 = 0.f, acc2 = 0.f, acc3 = 0.f;
    const float4 z4 = make_float4(0.f, 0.f, 0.f, 0.f);
    for (int st = 0; st < 8; ++st) {
        __syncthreads();
        for (int idx = t; idx < 9216; idx += 1024) {
            int kk = st * 144 + (idx >> 6);
            wlds[idx] = wtv(o, kk, idx & 63);
        }
        for (int f = t; f < 864; f += 1024) {
            int x4 = f % 18, rc = f / 18;
            int ry = rc >> 4, cl = rc & 15;
            int gr = i - 1 + ry;
            float4 val = z4;
            if (x4 >= 1 && x4 <= 16 && gr >= 0 && gr <= 63)
                val = *(const float4*)(catp(o, b * 128 + st * 16 + cl) + gr * 64 + (x4 - 1) * 4);
            *(float4*)(xlds + rc * 72 + x4 * 4) = val;
        }
        __syncthreads();
        for (int cl = 0; cl < 16; ++cl) {
            #pragma unroll
            for (int ry = 0; ry < 3; ++ry) {
                float w0  = wlds[(cl * 9 + ry * 3 + 0) * 64 + co];
                float w1f = wlds[(cl * 9 + ry * 3 + 1) * 64 + co];
                float w2  = wlds[(cl * 9 + ry * 3 + 2) * 64 + co];
                const float* xr = xlds + (ry * 16 + cl) * 72 + jg * 4;
                float4 q0 = *(const float4*)(xr);
                float4 q1 = *(const float4*)(xr + 4);
                float4 q2 = *(const float4*)(xr + 8);
                float xv[12] = { q0.x,q0.y,q0.z,q0.w, q1.x,q1.y,q1.z,q1.w, q2.x,q2.y,q2.z,q2.w };
                acc0 = fmaf(w0, xv[3], fmaf(w1f, xv[4], fmaf(w2, xv[5], acc0)));
                acc1 = fmaf(w0, xv[4], fmaf(w1f, xv[5], fmaf(w2, xv[6], acc1)));
                acc2 = fmaf(w0, xv[5], fmaf(w1f, xv[6], fmaf(w2, xv[7], acc2)));
                acc3 = fmaf(w0, xv[6], fmaf(w1f, xv[7], fmaf(w2, xv[8], acc3)));
            }
        }
    }
    float sc = g[co] * rsqrtf(v[co] + 1e-5f);
    float sh = b1[co] - m[co];
    float bb = be[co];
    float4 ov;
    ov.x = fmaxf(0.f, fmaf(acc0 + sh, sc, bb));
    ov.y = fmaxf(0.f, fmaf(acc1 + sh, sc, bb));
    ov.z = fmaxf(0.f, fmaf(acc2 + sh, sc, bb));
    ov.w = fmaxf(0.f, fmaf(acc3 + sh, sc, bb));
    *(float4*)(o + (size_t)(b * 64 + co) * 65536 + i * 64 + jg * 4) = ov;
}

// ---------------- K4a: per-plane spatial mean -> slot[12288]
__global__ __launch_bounds__(256) void k4_mean(float* __restrict__ o) {
    int q = blockIdx.x, t = threadIdx.x;
    const float* p = o + (size_t)q * 65536;
    float s = 0.f;
    for (int k = t; k < 4096; k += 256) s += p[k];
    #pragma unroll
    for (int off = 32; off > 0; off >>= 1) s += __shfl_down(s, off, 64);
    __shared__ float red[4];
    if ((t & 63) == 0) red[t >> 6] = s;
    __syncthreads();
    if (t == 0) o[(size_t)q * 65536 + 12288] = (red[0] + red[1] + red[2] + red[3]) * (1.f / 4096.f);
}

// ---------------- K4b: 1x1 conv + BN + sigmoid -> slot[12289]
__global__ __launch_bounds__(256) void k4_att(float* __restrict__ o, const float* __restrict__ wa,
    const float* __restrict__ g, const float* __restrict__ be, const float* __restrict__ m, const float* __restrict__ v) {
    int t = threadIdx.x;
    int b = t >> 6, co = t & 63;
    const float* wr = wa + co * 64;
    float s = 0.f;
    for (int ci = 0; ci < 64; ++ci) s = fmaf(wr[ci], o[(size_t)(b * 64 + ci) * 65536 + 12288], s);
    float sc = g[co] * rsqrtf(v[co] + 1e-5f);
    float y = fmaf(s - m[co], sc, be[co]);
    o[(size_t)t * 65536 + 12289] = 1.f / (1.f + expf(-y));
}

// ---------------- K5: out = bilinear_x4(feat)*att, in place over own slot. block 1024.
__global__ __launch_bounds__(1024) void k5_up(float* __restrict__ o) {
    __shared__ __align__(16) float fplane[4096];
    int bc = blockIdx.x;
    int t = threadIdx.x;
    float* slot = o + (size_t)bc * 65536;
    *(float4*)(fplane + t * 4) = *(const float4*)(slot + t * 4);
    float att = slot[12289];
    __syncthreads();
    int ox = t & 255, oyc = t >> 8;
    float fx = ox * 0.25f - 0.375f;
    int ix = (int)floorf(fx);
    float wx = fx - (float)ix;
    int x0 = ix < 0 ? 0 : ix;
    int x1 = (ix + 1 > 63) ? 63 : ix + 1;
    for (int oy = oyc * 64; oy < oyc * 64 + 64; ++oy) {
        float fy = oy * 0.25f - 0.375f;
        int iy = (int)floorf(fy);
        float wy = fy - (float)iy;
        int y0 = iy < 0 ? 0 : iy;
        int y1 = (iy + 1 > 63) ? 63 : iy + 1;
        float a  = fplane[y0 * 64 + x0], b_ = fplane[y0 * 64 + x1];
        float c_ = fplane[y1 * 64 + x0], d_ = fplane[y1 * 64 + x1];
        float top = a + wx * (b_ - a);
        float bot = c_ + wx * (d_ - c_);
        float val = (top + wy * (bot - top)) * att;
        slot[oy * 256 + ox] = val;
    }
}

extern "C" void kernel_launch(void* const* d_in, const int* in_sizes, int n_in,
                              void* d_out, int out_size, void* d_ws, size_t ws_size,
                              hipStream_t stream) {
    const float* x     = (const float*)d_in[0];
    const float* wd    = (const float*)d_in[1];
    const float* bd    = (const float*)d_in[2];
    const float* bnd_g = (const float*)d_in[3];
    const float* bnd_b = (const float*)d_in[4];
    const float* bnd_m = (const float*)d_in[5];
    const float* bnd_v = (const float*)d_in[6];
    const float* w1    = (const float*)d_in[7];
    const float* b1    = (const float*)d_in[8];
    const float* bn1_g = (const float*)d_in[9];
    const float* bn1_b = (const float*)d_in[10];
    const float* bn1_m = (const float*)d_in[11];
    const float* bn1_v = (const float*)d_in[12];
    const float* wa    = (const float*)d_in[13];
    const float* bna_g = (const float*)d_in[14];
    const float* bna_b = (const float*)d_in[15];
    const float* bna_m = (const float*)d_in[16];
    const float* bna_v = (const float*)d_in[17];

    float* o = (float*)d_out;

    hipLaunchKernelGGL(k0_wtrans, dim3(544), dim3(256), 0, stream, w1, wd, o);
    hipLaunchKernelGGL(k1_convds, dim3(512), dim3(256), 0, stream,
                       x, bd, bnd_g, bnd_b, bnd_m, bnd_v, o);
    hipLaunchKernelGGL(k2_feat, dim3(256), dim3(512), 0, stream, o);
    hipLaunchKernelGGL(k3_conv, dim3(256), dim3(1024), 0, stream,
                       o, b1, bn1_g, bn1_b, bn1_m, bn1_v);
    hipLaunchKernelGGL(k4_mean, dim3(256), dim3(256), 0, stream, o);
    hipLaunchKernelGGL(k4_att, dim3(1), dim3(256), 0, stream,
                       o, wa, bna_g, bna_b, bna_m, bna_v);
    hipLaunchKernelGGL(k5_up, dim3(256), dim3(1024), 0, stream, o);
}

// Round 19
// 240.416 us; speedup vs baseline: 1.4528x; 1.0362x over previous
//
#include <hip/hip_runtime.h>
#include <hip/hip_bf16.h>
#include <stdint.h>

// ---- All intermediates live inside d_out (16,777,216 f32; 256 slots x 65536 f32).
// Slot q (q=b*64+co): [0,4096) feat plane q ; [4096,8192) cat plane p (p<256, p&255==q)
// [8192,12288) cat plane p (p>=256) ; [12288] mean ; [12289] att ;
// [16384,24576) f64 x1_hi plane q ; [25600,26112) wT chunks ; [26624,27136) wdT64 chunks (f64).
__device__ __forceinline__ float* catp(float* o, int p) {
    return o + (size_t)(p & 255) * 65536 + 4096 + ((p >> 8) << 12);
}
__device__ __forceinline__ double* x1hp(float* o, int q) {
    return (double*)(o + (size_t)q * 65536 + 16384);
}
__device__ __forceinline__ float wtv(const float* o, int kk, int co) {
    return o[(size_t)(kk >> 3) * 65536 + 25600 + (kk & 7) * 64 + co];
}
__device__ __forceinline__ double* wd64p(float* o, int k) {   // + co
    return (double*)(o + (size_t)(k >> 2) * 65536 + 26624) + (k & 3) * 64;
}

// ---------------- K0: w1 -> wT[kk][co] (f32); wd -> wdT64[k][co] (f64)
__global__ __launch_bounds__(256) void k0_wtrans(const float* __restrict__ w1, const float* __restrict__ wd,
                                                 float* __restrict__ o) {
    int idx = blockIdx.x * 256 + threadIdx.x;
    if (idx < 73728) {
        int co = idx & 63, kk = idx >> 6;
        o[(size_t)(kk >> 3) * 65536 + 25600 + (kk & 7) * 64 + co] = w1[co * 1152 + kk];
    } else if (idx < 139264) {
        int j = idx - 73728;
        int co = j & 63, k = j >> 6;
        wd64p(o, k)[co] = (double)wd[co * 1024 + k];
    }
}

// ---------------- K1: 4x4/stride-4 conv + BN + ReLU as f64 register-blocked GEMM
// grid: 512 = (b,i,jh); block 256; thread = 4co x 2j. LDS 24KB. Bit-identical outputs.
__global__ __launch_bounds__(256) void k1_convds(
    const float* __restrict__ x, const float* __restrict__ bd,
    const float* __restrict__ g, const float* __restrict__ be,
    const float* __restrict__ m, const float* __restrict__ v,
    float* __restrict__ o)
{
    __shared__ __align__(16) double wlds[32 * 64];   // 16KB
    __shared__ __align__(16) double xlds[32 * 32];   // 8KB
    int blk = blockIdx.x;
    int jh = blk & 1, i = (blk >> 1) & 63, b = blk >> 7;
    int t = threadIdx.x;
    int tj = t & 15, tc = t >> 4;
    double acc[4][2];
    #pragma unroll
    for (int c = 0; c < 4; ++c) { acc[c][0] = 0.0; acc[c][1] = 0.0; }
    for (int p = 0; p < 32; ++p) {
        __syncthreads();
        #pragma unroll
        for (int u = 0; u < 8; ++u) {
            int idx = t + u * 256;
            int kl = idx >> 6, co = idx & 63;
            wlds[kl * 64 + co] = wd64p(o, p * 32 + kl)[co];
        }
        {
            int f4j = t & 31, ky = (t >> 5) & 3, ciL = t >> 7;
            const float* src = x + (((size_t)(b * 64 + p * 2 + ciL) * 256 + (i * 4 + ky)) * 256 + jh * 128 + f4j * 4);
            float4 f = *(const float4*)src;
            int kq = (ciL * 16 + ky * 4) * 32 + f4j;
            xlds[kq]      = (double)f.x;
            xlds[kq + 32] = (double)f.y;
            xlds[kq + 64] = (double)f.z;
            xlds[kq + 96] = (double)f.w;
        }
        __syncthreads();
        #pragma unroll
        for (int ciL = 0; ciL < 2; ++ciL) {
            #pragma unroll
            for (int ky = 0; ky < 4; ++ky) {
                int kq = ciL * 16 + ky * 4;
                double w_[4][4], x_[4][2];
                #pragma unroll
                for (int kx = 0; kx < 4; ++kx) {
                    const double* wp = wlds + (kq + kx) * 64;
                    const double* xp = xlds + (kq + kx) * 32;
                    double2 wa0 = *(const double2*)(wp + tc * 2);
                    double2 wa1 = *(const double2*)(wp + tc * 2 + 32);
                    double2 xa0 = *(const double2*)(xp + tj * 2);
                    w_[kx][0] = wa0.x; w_[kx][1] = wa0.y; w_[kx][2] = wa1.x; w_[kx][3] = wa1.y;
                    x_[kx][0] = xa0.x; x_[kx][1] = xa0.y;
                }
                #pragma unroll
                for (int c = 0; c < 4; ++c)
                    #pragma unroll
                    for (int jj = 0; jj < 2; ++jj)
                        acc[c][jj] = fma(w_[0][c], x_[0][jj],
                                     fma(w_[1][c], x_[1][jj],
                                     fma(w_[2][c], x_[2][jj],
                                     fma(w_[3][c], x_[3][jj], acc[c][jj]))));
            }
        }
    }
    #pragma unroll
    for (int c = 0; c < 4; ++c) {
        int co = ((c >> 1) << 5) + tc * 2 + (c & 1);
        double sc = (double)g[co] / sqrt((double)v[co] + 1e-5);
        double sh = (double)bd[co] - (double)m[co];
        double bb = (double)be[co];
        double o0v = fmax(0.0, (acc[c][0] + sh) * sc + bb);
        double o1v = fmax(0.0, (acc[c][1] + sh) * sc + bb);
        int pos0 = i * 64 + jh * 32 + tj * 2;
        float* cp = catp(o, b * 128 + co);
        *(float2*)(cp + pos0) = make_float2((float)o0v, (float)o1v);
        double* xh = x1hp(o, b * 64 + co);
        *(double2*)(xh + pos0) = make_double2(o0v, o1v);
    }
}

// ---------------- K2: windowed d^2 (f64, register-accumulated) -> top-9 -> f32 gather. block 512.
// 8 stages of 8 channels; LDS ~35.4KB (tile_d aliased with d2s and phase-4 tileq).
__global__ __launch_bounds__(512) void k2_feat(float* __restrict__ o)
{
    __shared__ __align__(16) char smem[29568];   // tile_d[56][66] f64 | d2s[64*50] f64 | tileq[56][68] f32
    __shared__ double sqd[7 * 64];
    __shared__ int sels[64 * 9];
    double* tile_d = (double*)smem;
    double* d2s = (double*)smem;
    float* tileq = (float*)smem;
    int blk = blockIdx.x;
    int b = blk >> 6, i = blk & 63;
    int t = threadIdx.x;
    int lane = t & 63, wv = t >> 6;   // wv 0..7

    double dacc[7];
    #pragma unroll
    for (int k = 0; k < 7; ++k) dacc[k] = 0.0;
    double sq_own = 0.0;

    // phase 1: 8 stages of 8 channels; dots + sq accumulate in REGISTERS
    for (int q = 0; q < 8; ++q) {
        __syncthreads();
        for (int s = t; s < 1792; s += 512) {       // 7r x 8c x 32 double2 chunks
            int rc = s >> 5, c2 = s & 31;
            int r = rc >> 3, c = rc & 7;
            int gr = i - 3 + r;
            if (gr >= 0 && gr <= 63) {
                const double* src = x1hp(o, b * 64 + q * 8 + c);
                *(double2*)(tile_d + rc * 66 + c2 * 2) = *(const double2*)(src + gr * 64 + c2 * 2);
            }
        }
        __syncthreads();
        if (t < 448) {
            int r = t >> 6, col = t & 63;
            int gr = i - 3 + r;
            if (gr >= 0 && gr <= 63) {
                double s = 0.0;
                #pragma unroll
                for (int c = 0; c < 8; ++c) {
                    double xv = tile_d[(r * 8 + c) * 66 + col];
                    s = fma(xv, xv, s);
                }
                sq_own += s;
            }
        }
        double xlq[8];
        #pragma unroll
        for (int c = 0; c < 8; ++c) xlq[c] = tile_d[(24 + c) * 66 + lane];
        #pragma unroll
        for (int k = 0; k < 7; ++k) {
            int oo = wv + 8 * k;
            if (oo < 49) {
                int oi = oo / 7 - 3, oj = oo % 7 - 3;
                int mi = i + oi, mj = lane + oj;
                if (mi >= 0 && mi <= 63 && mj >= 0 && mj <= 63) {
                    int r = oi + 3;
                    double dot = 0.0;
                    #pragma unroll
                    for (int c = 0; c < 8; ++c) dot = fma(xlq[c], tile_d[(r * 8 + c) * 66 + mj], dot);
                    dacc[k] += dot;
                }
            }
        }
    }
    __syncthreads();                 // all tile reads done
    if (t < 448) sqd[t] = sq_own;
    __syncthreads();                 // sqd visible; tile memory now dead -> reuse as d2s
    #pragma unroll
    for (int k = 0; k < 7; ++k) {
        int oo = wv + 8 * k;
        if (oo < 49) {
            int oi = oo / 7 - 3, oj = oo % 7 - 3;
            int mi = i + oi, mj = lane + oj;
            double d2 = -1e300;
            if (mi >= 0 && mi <= 63 && mj >= 0 && mj <= 63)
                d2 = sqd[192 + lane] + sqd[(oi + 3) * 64 + mj] - 2.0 * dacc[k];
            d2s[lane * 50 + oo] = d2;
        }
    }
    __syncthreads();
    // top-9 largest d^2 (ties -> lower window index)
    if (wv == 0) {
        unsigned long long mask = 0ull;
        for (int k = 0; k < 9; ++k) {
            double best = -1e308; int bi = 0;
            for (int oo = 0; oo < 49; ++oo) {
                if ((mask >> oo) & 1ull) continue;
                double vv = d2s[lane * 50 + oo];
                if (vv > best) { best = vv; bi = oo; }
            }
            mask |= (1ull << bi);
            sels[lane * 9 + k] = bi;
        }
    }
    __syncthreads();
    int rk[9], cj[9];
    #pragma unroll
    for (int k = 0; k < 9; ++k) {
        int oo = sels[lane * 9 + k];
        rk[k] = oo / 7;
        cj[k] = lane + (oo % 7) - 3;
    }
    // phase 4: f32 gather mean over selected neighbors, 8 stages of 8 channels
    for (int q = 0; q < 8; ++q) {
        __syncthreads();
        for (int s = t; s < 896; s += 512) {
            int rc = s >> 4, x4 = s & 15;
            int r = rc >> 3, c = rc & 7;
            int gr = i - 3 + r;
            if (gr >= 0 && gr <= 63)
                *(float4*)(tileq + rc * 68 + x4 * 4) =
                    *(const float4*)(catp(o, b * 128 + q * 8 + c) + gr * 64 + x4 * 4);
        }
        __syncthreads();
        {
            int c = wv;
            float s = 0.f;
            #pragma unroll
            for (int k = 0; k < 9; ++k) s += tileq[(rk[k] * 8 + c) * 68 + cj[k]];
            float outv = s * (1.f / 9.f) - tileq[(24 + c) * 68 + lane];
            catp(o, b * 128 + 64 + q * 8 + c)[i * 64 + lane] = outv;
        }
    }
}

// ---------------- K3: 3x3 conv (128->64) + BN + ReLU, LDS-staged weights+inputs
// grid: 256 = B*64 rows; block 1024. LDS 49.5KB. 8 stages of 16 ci.
__global__ __launch_bounds__(1024) void k3_conv(
    float* __restrict__ o, const float* __restrict__ b1,
    const float* __restrict__ g, const float* __restrict__ be,
    const float* __restrict__ m, const float* __restrict__ v)
{
    __shared__ __align__(16) float wlds[16 * 9 * 64];
    __shared__ __align__(16) float xlds[3 * 16 * 72];
    int blk = blockIdx.x;
    int b = blk >> 6, i = blk & 63;
    int t = threadIdx.x;
    int co = t & 63, jg = t >> 6;
    float acc0 = 0.f, acc1 = 0.f, acc2 = 0.f, acc3 = 0.f;
    const float4 z4 = make_float4(0.f, 0.f, 0.f, 0.f);
    for (int st = 0; st < 8; ++st) {
        __syncthreads();
        for (int idx = t; idx < 9216; idx += 1024) {
            int kk = st * 144 + (idx >> 6);
            wlds[idx] = wtv(o, kk, idx & 63);
        }
        for (int f = t; f < 864; f += 1024) {
            int x4 = f % 18, rc = f / 18;
            int ry = rc >> 4, cl = rc & 15;
            int gr = i - 1 + ry;
            float4 val = z4;
            if (x4 >= 1 && x4 <= 16 && gr >= 0 && gr <= 63)
                val = *(const float4*)(catp(o, b * 128 + st * 16 + cl) + gr * 64 + (x4 - 1) * 4);
            *(float4*)(xlds + rc * 72 + x4 * 4) = val;
        }
        __syncthreads();
        for (int cl = 0; cl < 16; ++cl) {
            #pragma unroll
            for (int ry = 0; ry < 3; ++ry) {
                float w0  = wlds[(cl * 9 + ry * 3 + 0) * 64 + co];
                float w1f = wlds[(cl * 9 + ry * 3 + 1) * 64 + co];
                float w2  = wlds[(cl * 9 + ry * 3 + 2) * 64 + co];
                const float* xr = xlds + (ry * 16 + cl) * 72 + jg * 4;
                float4 q0 = *(const float4*)(xr);
                float4 q1 = *(const float4*)(xr + 4);
                float4 q2 = *(const float4*)(xr + 8);
                float xv[12] = { q0.x,q0.y,q0.z,q0.w, q1.x,q1.y,q1.z,q1.w, q2.x,q2.y,q2.z,q2.w };
                acc0 = fmaf(w0, xv[3], fmaf(w1f, xv[4], fmaf(w2, xv[5], acc0)));
                acc1 = fmaf(w0, xv[4], fmaf(w1f, xv[5], fmaf(w2, xv[6], acc1)));
                acc2 = fmaf(w0, xv[5], fmaf(w1f, xv[6], fmaf(w2, xv[7], acc2)));
                acc3 = fmaf(w0, xv[6], fmaf(w1f, xv[7], fmaf(w2, xv[8], acc3)));
            }
        }
    }
    float sc = g[co] * rsqrtf(v[co] + 1e-5f);
    float sh = b1[co] - m[co];
    float bb = be[co];
    float4 ov;
    ov.x = fmaxf(0.f, fmaf(acc0 + sh, sc, bb));
    ov.y = fmaxf(0.f, fmaf(acc1 + sh, sc, bb));
    ov.z = fmaxf(0.f, fmaf(acc2 + sh, sc, bb));
    ov.w = fmaxf(0.f, fmaf(acc3 + sh, sc, bb));
    *(float4*)(o + (size_t)(b * 64 + co) * 65536 + i * 64 + jg * 4) = ov;
}

// ---------------- K4a: per-plane spatial mean -> slot[12288]
__global__ __launch_bounds__(256) void k4_mean(float* __restrict__ o) {
    int q = blockIdx.x, t = threadIdx.x;
    const float* p = o + (size_t)q * 65536;
    float s = 0.f;
    for (int k = t; k < 4096; k += 256) s += p[k];
    #pragma unroll
    for (int off = 32; off > 0; off >>= 1) s += __shfl_down(s, off, 64);
    __shared__ float red[4];
    if ((t & 63) == 0) red[t >> 6] = s;
    __syncthreads();
    if (t == 0) o[(size_t)q * 65536 + 12288] = (red[0] + red[1] + red[2] + red[3]) * (1.f / 4096.f);
}

// ---------------- K4b: 1x1 conv + BN + sigmoid -> slot[12289]
__global__ __launch_bounds__(256) void k4_att(float* __restrict__ o, const float* __restrict__ wa,
    const float* __restrict__ g, const float* __restrict__ be, const float* __restrict__ m, const float* __restrict__ v) {
    int t = threadIdx.x;
    int b = t >> 6, co = t & 63;
    const float* wr = wa + co * 64;
    float s = 0.f;
    for (int ci = 0; ci < 64; ++ci) s = fmaf(wr[ci], o[(size_t)(b * 64 + ci) * 65536 + 12288], s);
    float sc = g[co] * rsqrtf(v[co] + 1e-5f);
    float y = fmaf(s - m[co], sc, be[co]);
    o[(size_t)t * 65536 + 12289] = 1.f / (1.f + expf(-y));
}

// ---------------- K5: out = bilinear_x4(feat)*att, in place over own slot. block 1024.
__global__ __launch_bounds__(1024) void k5_up(float* __restrict__ o) {
    __shared__ __align__(16) float fplane[4096];
    int bc = blockIdx.x;
    int t = threadIdx.x;
    float* slot = o + (size_t)bc * 65536;
    *(float4*)(fplane + t * 4) = *(const float4*)(slot + t * 4);
    float att = slot[12289];
    __syncthreads();
    int ox = t & 255, oyc = t >> 8;
    float fx = ox * 0.25f - 0.375f;
    int ix = (int)floorf(fx);
    float wx = fx - (float)ix;
    int x0 = ix < 0 ? 0 : ix;
    int x1 = (ix + 1 > 63) ? 63 : ix + 1;
    for (int oy = oyc * 64; oy < oyc * 64 + 64; ++oy) {
        float fy = oy * 0.25f - 0.375f;
        int iy = (int)floorf(fy);
        float wy = fy - (float)iy;
        int y0 = iy < 0 ? 0 : iy;
        int y1 = (iy + 1 > 63) ? 63 : iy + 1;
        float a  = fplane[y0 * 64 + x0], b_ = fplane[y0 * 64 + x1];
        float c_ = fplane[y1 * 64 + x0], d_ = fplane[y1 * 64 + x1];
        float top = a + wx * (b_ - a);
        float bot = c_ + wx * (d_ - c_);
        float val = (top + wy * (bot - top)) * att;
        slot[oy * 256 + ox] = val;
    }
}

extern "C" void kernel_launch(void* const* d_in, const int* in_sizes, int n_in,
                              void* d_out, int out_size, void* d_ws, size_t ws_size,
                              hipStream_t stream) {
    const float* x     = (const float*)d_in[0];
    const float* wd    = (const float*)d_in[1];
    const float* bd    = (const float*)d_in[2];
    const float* bnd_g = (const float*)d_in[3];
    const float* bnd_b = (const float*)d_in[4];
    const float* bnd_m = (const float*)d_in[5];
    const float* bnd_v = (const float*)d_in[6];
    const float* w1    = (const float*)d_in[7];
    const float* b1    = (const float*)d_in[8];
    const float* bn1_g = (const float*)d_in[9];
    const float* bn1_b = (const float*)d_in[10];
    const float* bn1_m = (const float*)d_in[11];
    const float* bn1_v = (const float*)d_in[12];
    const float* wa    = (const float*)d_in[13];
    const float* bna_g = (const float*)d_in[14];
    const float* bna_b = (const float*)d_in[15];
    const float* bna_m = (const float*)d_in[16];
    const float* bna_v = (const float*)d_in[17];

    float* o = (float*)d_out;

    hipLaunchKernelGGL(k0_wtrans, dim3(544), dim3(256), 0, stream, w1, wd, o);
    hipLaunchKernelGGL(k1_convds, dim3(512), dim3(256), 0, stream,
                       x, bd, bnd_g, bnd_b, bnd_m, bnd_v, o);
    hipLaunchKernelGGL(k2_feat, dim3(256), dim3(512), 0, stream, o);
    hipLaunchKernelGGL(k3_conv, dim3(256), dim3(1024), 0, stream,
                       o, b1, bn1_g, bn1_b, bn1_m, bn1_v);
    hipLaunchKernelGGL(k4_mean, dim3(256), dim3(256), 0, stream, o);
    hipLaunchKernelGGL(k4_att, dim3(1), dim3(256), 0, stream,
                       o, wa, bna_g, bna_b, bna_m, bna_v);
    hipLaunchKernelGGL(k5_up, dim3(256), dim3(1024), 0, stream, o);
}

// Round 20
// 240.281 us; speedup vs baseline: 1.4536x; 1.0006x over previous
//
#include <hip/hip_runtime.h>
#include <hip/hip_bf16.h>
#include <stdint.h>

// ---- All intermediates live inside d_out (16,777,216 f32; 256 slots x 65536 f32).
// Slot q (q=b*64+co): [0,4096) feat plane q ; [4096,8192) cat plane p (p<256, p&255==q)
// [8192,12288) cat plane p (p>=256) ; [12288] mean ; [12289] att ;
// [16384,24576) f64 x1_hi plane q ; [25600,26112) wT chunks ; [26624,27136) wdT64 chunks (f64).
__device__ __forceinline__ float* catp(float* o, int p) {
    return o + (size_t)(p & 255) * 65536 + 4096 + ((p >> 8) << 12);
}
__device__ __forceinline__ double* x1hp(float* o, int q) {
    return (double*)(o + (size_t)q * 65536 + 16384);
}
__device__ __forceinline__ float wtv(const float* o, int kk, int co) {
    return o[(size_t)(kk >> 3) * 65536 + 25600 + (kk & 7) * 64 + co];
}
__device__ __forceinline__ double* wd64p(float* o, int k) {   // + co
    return (double*)(o + (size_t)(k >> 2) * 65536 + 26624) + (k & 3) * 64;
}

// ---------------- K0: w1 -> wT[kk][co] (f32); wd -> wdT64[k][co] (f64)
__global__ __launch_bounds__(256) void k0_wtrans(const float* __restrict__ w1, const float* __restrict__ wd,
                                                 float* __restrict__ o) {
    int idx = blockIdx.x * 256 + threadIdx.x;
    if (idx < 73728) {
        int co = idx & 63, kk = idx >> 6;
        o[(size_t)(kk >> 3) * 65536 + 25600 + (kk & 7) * 64 + co] = w1[co * 1152 + kk];
    } else if (idx < 139264) {
        int j = idx - 73728;
        int co = j & 63, k = j >> 6;
        wd64p(o, k)[co] = (double)wd[co * 1024 + k];
    }
}

// ---------------- K1: 4x4/stride-4 conv + BN + ReLU as f64 register-blocked GEMM
// grid: 512 = (b,i,jh); block 256; thread = 4co x 2j. Double-buffered LDS (48KB) +
// register prefetch: panel p+1 loads issue before compute(p); ONE barrier/panel.
// Bit-identical outputs (same FMA order per output).
__global__ __launch_bounds__(256) void k1_convds(
    const float* __restrict__ x, const float* __restrict__ bd,
    const float* __restrict__ g, const float* __restrict__ be,
    const float* __restrict__ m, const float* __restrict__ v,
    float* __restrict__ o)
{
    __shared__ __align__(16) double wlds[2][32 * 64];   // 2x16KB
    __shared__ __align__(16) double xlds[2][32 * 32];   // 2x8KB
    int blk = blockIdx.x;
    int jh = blk & 1, i = (blk >> 1) & 63, b = blk >> 7;
    int t = threadIdx.x;
    int tj = t & 15, tc = t >> 4;
    // staging assignment (fixed per thread)
    int s_f4j = t & 31, s_ky = (t >> 5) & 3, s_ciL = t >> 7;
    int s_kq = (s_ciL * 16 + s_ky * 4) * 32 + s_f4j;

    double acc[4][2];
    #pragma unroll
    for (int c = 0; c < 4; ++c) { acc[c][0] = 0.0; acc[c][1] = 0.0; }

    double wreg[8];
    float4 xreg;
    // prologue: load panel 0
    #pragma unroll
    for (int u = 0; u < 8; ++u) {
        int idx = t + u * 256;
        wreg[u] = wd64p(o, (idx >> 6))[idx & 63];
    }
    xreg = *(const float4*)(x + (((size_t)(b * 64 + s_ciL) * 256 + (i * 4 + s_ky)) * 256 + jh * 128 + s_f4j * 4));
    #pragma unroll
    for (int u = 0; u < 8; ++u) {
        int idx = t + u * 256;
        wlds[0][(idx >> 6) * 64 + (idx & 63)] = wreg[u];
    }
    xlds[0][s_kq]      = (double)xreg.x;
    xlds[0][s_kq + 32] = (double)xreg.y;
    xlds[0][s_kq + 64] = (double)xreg.z;
    xlds[0][s_kq + 96] = (double)xreg.w;
    __syncthreads();

    for (int p = 0; p < 32; ++p) {
        int cur = p & 1;
        if (p + 1 < 32) {
            // issue panel p+1 global loads (fly under compute)
            #pragma unroll
            for (int u = 0; u < 8; ++u) {
                int idx = t + u * 256;
                wreg[u] = wd64p(o, (p + 1) * 32 + (idx >> 6))[idx & 63];
            }
            xreg = *(const float4*)(x + (((size_t)(b * 64 + (p + 1) * 2 + s_ciL) * 256 + (i * 4 + s_ky)) * 256 + jh * 128 + s_f4j * 4));
        }
        // compute panel p from LDS buffer cur
        const double* wb = wlds[cur];
        const double* xb = xlds[cur];
        #pragma unroll
        for (int ciL = 0; ciL < 2; ++ciL) {
            #pragma unroll
            for (int ky = 0; ky < 4; ++ky) {
                int kq = ciL * 16 + ky * 4;
                double w_[4][4], x_[4][2];
                #pragma unroll
                for (int kx = 0; kx < 4; ++kx) {
                    const double* wp = wb + (kq + kx) * 64;
                    const double* xp = xb + (kq + kx) * 32;
                    double2 wa0 = *(const double2*)(wp + tc * 2);
                    double2 wa1 = *(const double2*)(wp + tc * 2 + 32);
                    double2 xa0 = *(const double2*)(xp + tj * 2);
                    w_[kx][0] = wa0.x; w_[kx][1] = wa0.y; w_[kx][2] = wa1.x; w_[kx][3] = wa1.y;
                    x_[kx][0] = xa0.x; x_[kx][1] = xa0.y;
                }
                #pragma unroll
                for (int c = 0; c < 4; ++c)
                    #pragma unroll
                    for (int jj = 0; jj < 2; ++jj)
                        acc[c][jj] = fma(w_[0][c], x_[0][jj],
                                     fma(w_[1][c], x_[1][jj],
                                     fma(w_[2][c], x_[2][jj],
                                     fma(w_[3][c], x_[3][jj], acc[c][jj]))));
            }
        }
        if (p + 1 < 32) {
            int nxt = (p + 1) & 1;
            #pragma unroll
            for (int u = 0; u < 8; ++u) {
                int idx = t + u * 256;
                wlds[nxt][(idx >> 6) * 64 + (idx & 63)] = wreg[u];
            }
            xlds[nxt][s_kq]      = (double)xreg.x;
            xlds[nxt][s_kq + 32] = (double)xreg.y;
            xlds[nxt][s_kq + 64] = (double)xreg.z;
            xlds[nxt][s_kq + 96] = (double)xreg.w;
            __syncthreads();
        }
    }
    #pragma unroll
    for (int c = 0; c < 4; ++c) {
        int co = ((c >> 1) << 5) + tc * 2 + (c & 1);
        double sc = (double)g[co] / sqrt((double)v[co] + 1e-5);
        double sh = (double)bd[co] - (double)m[co];
        double bb = (double)be[co];
        double o0v = fmax(0.0, (acc[c][0] + sh) * sc + bb);
        double o1v = fmax(0.0, (acc[c][1] + sh) * sc + bb);
        int pos0 = i * 64 + jh * 32 + tj * 2;
        float* cp = catp(o, b * 128 + co);
        *(float2*)(cp + pos0) = make_float2((float)o0v, (float)o1v);
        double* xh = x1hp(o, b * 64 + co);
        *(double2*)(xh + pos0) = make_double2(o0v, o1v);
    }
}

// ---------------- K2: windowed d^2 (f64, register-accumulated) -> top-9 -> f32 gather. block 512.
__global__ __launch_bounds__(512) void k2_feat(float* __restrict__ o)
{
    __shared__ __align__(16) char smem[29568];   // tile_d[56][66] f64 | d2s[64*50] f64 | tileq[56][68] f32
    __shared__ double sqd[7 * 64];
    __shared__ int sels[64 * 9];
    double* tile_d = (double*)smem;
    double* d2s = (double*)smem;
    float* tileq = (float*)smem;
    int blk = blockIdx.x;
    int b = blk >> 6, i = blk & 63;
    int t = threadIdx.x;
    int lane = t & 63, wv = t >> 6;

    double dacc[7];
    #pragma unroll
    for (int k = 0; k < 7; ++k) dacc[k] = 0.0;
    double sq_own = 0.0;

    for (int q = 0; q < 8; ++q) {
        __syncthreads();
        for (int s = t; s < 1792; s += 512) {
            int rc = s >> 5, c2 = s & 31;
            int r = rc >> 3, c = rc & 7;
            int gr = i - 3 + r;
            if (gr >= 0 && gr <= 63) {
                const double* src = x1hp(o, b * 64 + q * 8 + c);
                *(double2*)(tile_d + rc * 66 + c2 * 2) = *(const double2*)(src + gr * 64 + c2 * 2);
            }
        }
        __syncthreads();
        if (t < 448) {
            int r = t >> 6, col = t & 63;
            int gr = i - 3 + r;
            if (gr >= 0 && gr <= 63) {
                double s = 0.0;
                #pragma unroll
                for (int c = 0; c < 8; ++c) {
                    double xv = tile_d[(r * 8 + c) * 66 + col];
                    s = fma(xv, xv, s);
                }
                sq_own += s;
            }
        }
        double xlq[8];
        #pragma unroll
        for (int c = 0; c < 8; ++c) xlq[c] = tile_d[(24 + c) * 66 + lane];
        #pragma unroll
        for (int k = 0; k < 7; ++k) {
            int oo = wv + 8 * k;
            if (oo < 49) {
                int oi = oo / 7 - 3, oj = oo % 7 - 3;
                int mi = i + oi, mj = lane + oj;
                if (mi >= 0 && mi <= 63 && mj >= 0 && mj <= 63) {
                    int r = oi + 3;
                    double dot = 0.0;
                    #pragma unroll
                    for (int c = 0; c < 8; ++c) dot = fma(xlq[c], tile_d[(r * 8 + c) * 66 + mj], dot);
                    dacc[k] += dot;
                }
            }
        }
    }
    __syncthreads();
    if (t < 448) sqd[t] = sq_own;
    __syncthreads();
    #pragma unroll
    for (int k = 0; k < 7; ++k) {
        int oo = wv + 8 * k;
        if (oo < 49) {
            int oi = oo / 7 - 3, oj = oo % 7 - 3;
            int mi = i + oi, mj = lane + oj;
            double d2 = -1e300;
            if (mi >= 0 && mi <= 63 && mj >= 0 && mj <= 63)
                d2 = sqd[192 + lane] + sqd[(oi + 3) * 64 + mj] - 2.0 * dacc[k];
            d2s[lane * 50 + oo] = d2;
        }
    }
    __syncthreads();
    if (wv == 0) {
        unsigned long long mask = 0ull;
        for (int k = 0; k < 9; ++k) {
            double best = -1e308; int bi = 0;
            for (int oo = 0; oo < 49; ++oo) {
                if ((mask >> oo) & 1ull) continue;
                double vv = d2s[lane * 50 + oo];
                if (vv > best) { best = vv; bi = oo; }
            }
            mask |= (1ull << bi);
            sels[lane * 9 + k] = bi;
        }
    }
    __syncthreads();
    int rk[9], cj[9];
    #pragma unroll
    for (int k = 0; k < 9; ++k) {
        int oo = sels[lane * 9 + k];
        rk[k] = oo / 7;
        cj[k] = lane + (oo % 7) - 3;
    }
    for (int q = 0; q < 8; ++q) {
        __syncthreads();
        for (int s = t; s < 896; s += 512) {
            int rc = s >> 4, x4 = s & 15;
            int r = rc >> 3, c = rc & 7;
            int gr = i - 3 + r;
            if (gr >= 0 && gr <= 63)
                *(float4*)(tileq + rc * 68 + x4 * 4) =
                    *(const float4*)(catp(o, b * 128 + q * 8 + c) + gr * 64 + x4 * 4);
        }
        __syncthreads();
        {
            int c = wv;
            float s = 0.f;
            #pragma unroll
            for (int k = 0; k < 9; ++k) s += tileq[(rk[k] * 8 + c) * 68 + cj[k]];
            float outv = s * (1.f / 9.f) - tileq[(24 + c) * 68 + lane];
            catp(o, b * 128 + 64 + q * 8 + c)[i * 64 + lane] = outv;
        }
    }
}

// ---------------- K3: 3x3 conv (128->64) + BN + ReLU, LDS-staged weights+inputs
// grid: 256 = B*64 rows; block 1024. LDS 49.5KB. 8 stages of 16 ci.
__global__ __launch_bounds__(1024) void k3_conv(
    float* __restrict__ o, const float* __restrict__ b1,
    const float* __restrict__ g, const float* __restrict__ be,
    const float* __restrict__ m, const float* __restrict__ v)
{
    __shared__ __align__(16) float wlds[16 * 9 * 64];
    __shared__ __align__(16) float xlds[3 * 16 * 72];
    int blk = blockIdx.x;
    int b = blk >> 6, i = blk & 63;
    int t = threadIdx.x;
    int co = t & 63, jg = t >> 6;
    float acc0 = 0.f, acc1 = 0.f, acc2 = 0.f, acc3 = 0.f;
    const float4 z4 = make_float4(0.f, 0.f, 0.f, 0.f);
    for (int st = 0; st < 8; ++st) {
        __syncthreads();
        for (int idx = t; idx < 9216; idx += 1024) {
            int kk = st * 144 + (idx >> 6);
            wlds[idx] = wtv(o, kk, idx & 63);
        }
        for (int f = t; f < 864; f += 1024) {
            int x4 = f % 18, rc = f / 18;
            int ry = rc >> 4, cl = rc & 15;
            int gr = i - 1 + ry;
            float4 val = z4;
            if (x4 >= 1 && x4 <= 16 && gr >= 0 && gr <= 63)
                val = *(const float4*)(catp(o, b * 128 + st * 16 + cl) + gr * 64 + (x4 - 1) * 4);
            *(float4*)(xlds + rc * 72 + x4 * 4) = val;
        }
        __syncthreads();
        for (int cl = 0; cl < 16; ++cl) {
            #pragma unroll
            for (int ry = 0; ry < 3; ++ry) {
                float w0  = wlds[(cl * 9 + ry * 3 + 0) * 64 + co];
                float w1f = wlds[(cl * 9 + ry * 3 + 1) * 64 + co];
                float w2  = wlds[(cl * 9 + ry * 3 + 2) * 64 + co];
                const float* xr = xlds + (ry * 16 + cl) * 72 + jg * 4;
                float4 q0 = *(const float4*)(xr);
                float4 q1 = *(const float4*)(xr + 4);
                float4 q2 = *(const float4*)(xr + 8);
                float xv[12] = { q0.x,q0.y,q0.z,q0.w, q1.x,q1.y,q1.z,q1.w, q2.x,q2.y,q2.z,q2.w };
                acc0 = fmaf(w0, xv[3], fmaf(w1f, xv[4], fmaf(w2, xv[5], acc0)));
                acc1 = fmaf(w0, xv[4], fmaf(w1f, xv[5], fmaf(w2, xv[6], acc1)));
                acc2 = fmaf(w0, xv[5], fmaf(w1f, xv[6], fmaf(w2, xv[7], acc2)));
                acc3 = fmaf(w0, xv[6], fmaf(w1f, xv[7], fmaf(w2, xv[8], acc3)));
            }
        }
    }
    float sc = g[co] * rsqrtf(v[co] + 1e-5f);
    float sh = b1[co] - m[co];
    float bb = be[co];
    float4 ov;
    ov.x = fmaxf(0.f, fmaf(acc0 + sh, sc, bb));
    ov.y = fmaxf(0.f, fmaf(acc1 + sh, sc, bb));
    ov.z = fmaxf(0.f, fmaf(acc2 + sh, sc, bb));
    ov.w = fmaxf(0.f, fmaf(acc3 + sh, sc, bb));
    *(float4*)(o + (size_t)(b * 64 + co) * 65536 + i * 64 + jg * 4) = ov;
}

// ---------------- K4a: per-plane spatial mean -> slot[12288]
__global__ __launch_bounds__(256) void k4_mean(float* __restrict__ o) {
    int q = blockIdx.x, t = threadIdx.x;
    const float* p = o + (size_t)q * 65536;
    float s = 0.f;
    for (int k = t; k < 4096; k += 256) s += p[k];
    #pragma unroll
    for (int off = 32; off > 0; off >>= 1) s += __shfl_down(s, off, 64);
    __shared__ float red[4];
    if ((t & 63) == 0) red[t >> 6] = s;
    __syncthreads();
    if (t == 0) o[(size_t)q * 65536 + 12288] = (red[0] + red[1] + red[2] + red[3]) * (1.f / 4096.f);
}

// ---------------- K4b: 1x1 conv + BN + sigmoid -> slot[12289]
__global__ __launch_bounds__(256) void k4_att(float* __restrict__ o, const float* __restrict__ wa,
    const float* __restrict__ g, const float* __restrict__ be, const float* __restrict__ m, const float* __restrict__ v) {
    int t = threadIdx.x;
    int b = t >> 6, co = t & 63;
    const float* wr = wa + co * 64;
    float s = 0.f;
    for (int ci = 0; ci < 64; ++ci) s = fmaf(wr[ci], o[(size_t)(b * 64 + ci) * 65536 + 12288], s);
    float sc = g[co] * rsqrtf(v[co] + 1e-5f);
    float y = fmaf(s - m[co], sc, be[co]);
    o[(size_t)t * 65536 + 12289] = 1.f / (1.f + expf(-y));
}

// ---------------- K5: out = bilinear_x4(feat)*att, in place over own slot. block 1024.
__global__ __launch_bounds__(1024) void k5_up(float* __restrict__ o) {
    __shared__ __align__(16) float fplane[4096];
    int bc = blockIdx.x;
    int t = threadIdx.x;
    float* slot = o + (size_t)bc * 65536;
    *(float4*)(fplane + t * 4) = *(const float4*)(slot + t * 4);
    float att = slot[12289];
    __syncthreads();
    int ox = t & 255, oyc = t >> 8;
    float fx = ox * 0.25f - 0.375f;
    int ix = (int)floorf(fx);
    float wx = fx - (float)ix;
    int x0 = ix < 0 ? 0 : ix;
    int x1 = (ix + 1 > 63) ? 63 : ix + 1;
    for (int oy = oyc * 64; oy < oyc * 64 + 64; ++oy) {
        float fy = oy * 0.25f - 0.375f;
        int iy = (int)floorf(fy);
        float wy = fy - (float)iy;
        int y0 = iy < 0 ? 0 : iy;
        int y1 = (iy + 1 > 63) ? 63 : iy + 1;
        float a  = fplane[y0 * 64 + x0], b_ = fplane[y0 * 64 + x1];
        float c_ = fplane[y1 * 64 + x0], d_ = fplane[y1 * 64 + x1];
        float top = a + wx * (b_ - a);
        float bot = c_ + wx * (d_ - c_);
        float val = (top + wy * (bot - top)) * att;
        slot[oy * 256 + ox] = val;
    }
}

extern "C" void kernel_launch(void* const* d_in, const int* in_sizes, int n_in,
                              void* d_out, int out_size, void* d_ws, size_t ws_size,
                              hipStream_t stream) {
    const float* x     = (const float*)d_in[0];
    const float* wd    = (const float*)d_in[1];
    const float* bd    = (const float*)d_in[2];
    const float* bnd_g = (const float*)d_in[3];
    const float* bnd_b = (const float*)d_in[4];
    const float* bnd_m = (const float*)d_in[5];
    const float* bnd_v = (const float*)d_in[6];
    const float* w1    = (const float*)d_in[7];
    const float* b1    = (const float*)d_in[8];
    const float* bn1_g = (const float*)d_in[9];
    const float* bn1_b = (const float*)d_in[10];
    const float* bn1_m = (const float*)d_in[11];
    const float* bn1_v = (const float*)d_in[12];
    const float* wa    = (const float*)d_in[13];
    const float* bna_g = (const float*)d_in[14];
    const float* bna_b = (const float*)d_in[15];
    const float* bna_m = (const float*)d_in[16];
    const float* bna_v = (const float*)d_in[17];

    float* o = (float*)d_out;

    hipLaunchKernelGGL(k0_wtrans, dim3(544), dim3(256), 0, stream, w1, wd, o);
    hipLaunchKernelGGL(k1_convds, dim3(512), dim3(256), 0, stream,
                       x, bd, bnd_g, bnd_b, bnd_m, bnd_v, o);
    hipLaunchKernelGGL(k2_feat, dim3(256), dim3(512), 0, stream, o);
    hipLaunchKernelGGL(k3_conv, dim3(256), dim3(1024), 0, stream,
                       o, b1, bn1_g, bn1_b, bn1_m, bn1_v);
    hipLaunchKernelGGL(k4_mean, dim3(256), dim3(256), 0, stream, o);
    hipLaunchKernelGGL(k4_att, dim3(1), dim3(256), 0, stream,
                       o, wa, bna_g, bna_b, bna_m, bna_v);
    hipLaunchKernelGGL(k5_up, dim3(256), dim3(1024), 0, stream, o);
}